// Round 1
// baseline (1826.965 us; speedup 1.0000x reference)
//
#include <hip/hip_runtime.h>

#define N_NODES 50000
#define N_EDGESX 1600000
#define E_TOT   (N_EDGESX + N_NODES)
#define IN_DIM 128
#define HID 64
#define HEADS 4
#define HC 256
#define N_GRAPHS 64
#define OUT_DIM 10
#define NEG_SLOPE 0.2f

__device__ __forceinline__ float lrelu(float x){ return x > 0.f ? x : NEG_SLOPE*x; }
__device__ __forceinline__ float sel4(float4 v, int i){
  float r = v.x;
  r = (i==1) ? v.y : r;
  r = (i==2) ? v.z : r;
  r = (i==3) ? v.w : r;
  return r;
}

// ---------------- CSR build ----------------
__global__ __launch_bounds__(256) void hist_k(const int* __restrict__ ei, int* __restrict__ cnts){
  int e = blockIdx.x*256 + threadIdx.x;
  if (e >= E_TOT) return;
  int dst = (e < N_EDGESX) ? ei[N_EDGESX + e] : (e - N_EDGESX);
  atomicAdd(&cnts[dst], 1);
}

__global__ __launch_bounds__(1024) void scan_k(int* __restrict__ cnts, int* __restrict__ row_start, int N){
  __shared__ int tmp[1024];
  __shared__ int carry;
  if (threadIdx.x == 0) carry = 0;
  __syncthreads();
  for (int base = 0; base < N; base += 1024){
    int i = base + threadIdx.x;
    int v = (i < N) ? cnts[i] : 0;
    tmp[threadIdx.x] = v;
    __syncthreads();
    for (int off = 1; off < 1024; off <<= 1){
      int t = (threadIdx.x >= (unsigned)off) ? tmp[threadIdx.x - off] : 0;
      __syncthreads();
      tmp[threadIdx.x] += t;
      __syncthreads();
    }
    int excl = tmp[threadIdx.x] - v + carry;
    if (i < N){ row_start[i] = excl; cnts[i] = excl; }
    __syncthreads();
    if (threadIdx.x == 1023) carry += tmp[1023];
    __syncthreads();
  }
  if (threadIdx.x == 0) row_start[N] = carry;
}

__global__ __launch_bounds__(256) void scatter_k(const int* __restrict__ ei, int* __restrict__ cursor,
                                                 int* __restrict__ csr_src){
  int e = blockIdx.x*256 + threadIdx.x;
  if (e >= E_TOT) return;
  int src, dst;
  if (e < N_EDGESX){ src = ei[e]; dst = ei[N_EDGESX + e]; }
  else { src = e - N_EDGESX; dst = src; }
  int pos = atomicAdd(&cursor[dst], 1);
  csr_src[pos] = src;
}

// ---------------- aggregator linear: x0 = imgs @ W_agg + b_agg  [N,64] ----------------
__global__ __launch_bounds__(256) void agg_lin(const float* __restrict__ imgs, const float* __restrict__ W,
                                               const float* __restrict__ b, float* __restrict__ x0){
  __shared__ __align__(16) float xr[4][IN_DIM];
  int w = threadIdx.x >> 6, lane = threadIdx.x & 63;
  int n = blockIdx.x*4 + w;
  if (n >= N_NODES) return;
  ((float2*)xr[w])[lane] = ((const float2*)(imgs + (size_t)n*IN_DIM))[lane];
  float acc = b[lane];
  #pragma unroll 8
  for (int k = 0; k < IN_DIM; k++)
    acc = fmaf(xr[w][k], W[k*HID + lane], acc);
  x0[(size_t)n*HID + lane] = acc;
}

// ---------------- GAT linear: h = x @ W   [N,K] x [K,256] -> [N,256] ----------------
template<int K>
__global__ __launch_bounds__(256) void lin_k(const float* __restrict__ x, const float* __restrict__ W,
                                             float* __restrict__ h){
  __shared__ __align__(16) float xs[K][36];
  const int tid = threadIdx.x;
  const int cg = tid & 63;   // column group: cols cg*4..cg*4+3
  const int ng = tid >> 6;   // node group: nodes ng*8..ng*8+7 (== wave id)
  const int n0 = blockIdx.x * 32;
  for (int idx = tid; idx < 32*K; idx += 256){
    int r = idx / K, c = idx % K;
    int n = n0 + r;
    xs[c][r] = (n < N_NODES) ? x[(size_t)n*K + c] : 0.f;
  }
  __syncthreads();
  float acc[8][4];
  #pragma unroll
  for (int i = 0; i < 8; i++){
    acc[i][0]=0.f; acc[i][1]=0.f; acc[i][2]=0.f; acc[i][3]=0.f;
  }
  #pragma unroll 4
  for (int k = 0; k < K; k++){
    float4 wv = *(const float4*)(W + k*HC + cg*4);
    float4 a0 = *(const float4*)(&xs[k][ng*8]);
    float4 a1 = *(const float4*)(&xs[k][ng*8+4]);
    float xr[8] = {a0.x,a0.y,a0.z,a0.w,a1.x,a1.y,a1.z,a1.w};
    #pragma unroll
    for (int i = 0; i < 8; i++){
      acc[i][0] = fmaf(xr[i], wv.x, acc[i][0]);
      acc[i][1] = fmaf(xr[i], wv.y, acc[i][1]);
      acc[i][2] = fmaf(xr[i], wv.z, acc[i][2]);
      acc[i][3] = fmaf(xr[i], wv.w, acc[i][3]);
    }
  }
  #pragma unroll
  for (int i = 0; i < 8; i++){
    int n = n0 + ng*8 + i;
    if (n < N_NODES){
      float4 o; o.x=acc[i][0]; o.y=acc[i][1]; o.z=acc[i][2]; o.w=acc[i][3];
      *(float4*)(h + (size_t)n*HC + cg*4) = o;
    }
  }
}

// ---------------- per-node attention scores ----------------
__global__ __launch_bounds__(256) void scores_k(const float* __restrict__ h, const float* __restrict__ as,
                                                const float* __restrict__ ad, float* __restrict__ es,
                                                float* __restrict__ ed){
  int n = blockIdx.x;
  int lane = threadIdx.x & 63;
  int head = threadIdx.x >> 6;
  float v = h[(size_t)n*HC + head*HID + lane];
  float ps = v * as[head*HID + lane];
  float pd = v * ad[head*HID + lane];
  #pragma unroll
  for (int off = 32; off >= 1; off >>= 1){
    ps += __shfl_xor(ps, off);
    pd += __shfl_xor(pd, off);
  }
  if (lane == 0){ es[n*4 + head] = ps; ed[n*4 + head] = pd; }
}

// ---------------- GAT aggregation: one wave per dst node, CSR gather ----------------
__global__ __launch_bounds__(256) void gat_agg(const float* __restrict__ h, const float* __restrict__ es,
    const float* __restrict__ ed, const int* __restrict__ row_start, const int* __restrict__ csr_src,
    float* __restrict__ out){
  int lane = threadIdx.x & 63;
  int n = blockIdx.x*4 + (threadIdx.x >> 6);
  if (n >= N_NODES) return;
  int rs = row_start[n], re = row_start[n+1];
  float4 edn = *(const float4*)(ed + n*4);
  // phase 1: segment max (strided over lanes, then butterfly)
  float4 mx = make_float4(-1e30f,-1e30f,-1e30f,-1e30f);
  for (int e = rs + lane; e < re; e += 64){
    int s = csr_src[e];
    float4 e4 = *(const float4*)(es + s*4);
    mx.x = fmaxf(mx.x, lrelu(e4.x + edn.x));
    mx.y = fmaxf(mx.y, lrelu(e4.y + edn.y));
    mx.z = fmaxf(mx.z, lrelu(e4.z + edn.z));
    mx.w = fmaxf(mx.w, lrelu(e4.w + edn.w));
  }
  #pragma unroll
  for (int off = 32; off >= 1; off >>= 1){
    mx.x = fmaxf(mx.x, __shfl_xor(mx.x, off));
    mx.y = fmaxf(mx.y, __shfl_xor(mx.y, off));
    mx.z = fmaxf(mx.z, __shfl_xor(mx.z, off));
    mx.w = fmaxf(mx.w, __shfl_xor(mx.w, off));
  }
  // phase 2: segment sum of exp
  float4 sm = make_float4(0.f,0.f,0.f,0.f);
  for (int e = rs + lane; e < re; e += 64){
    int s = csr_src[e];
    float4 e4 = *(const float4*)(es + s*4);
    sm.x += __expf(lrelu(e4.x + edn.x) - mx.x);
    sm.y += __expf(lrelu(e4.y + edn.y) - mx.y);
    sm.z += __expf(lrelu(e4.z + edn.z) - mx.z);
    sm.w += __expf(lrelu(e4.w + edn.w) - mx.w);
  }
  #pragma unroll
  for (int off = 32; off >= 1; off >>= 1){
    sm.x += __shfl_xor(sm.x, off);
    sm.y += __shfl_xor(sm.y, off);
    sm.z += __shfl_xor(sm.z, off);
    sm.w += __shfl_xor(sm.w, off);
  }
  // phase 3: weighted feature gather; lane owns 4 contiguous feature dims (one head)
  int hh = lane >> 4;
  float m_h  = sel4(mx, hh);
  float ed_h = sel4(edn, hh);
  float inv_h = 1.f / (sel4(sm, hh) + 1e-16f);
  float4 acc = make_float4(0.f,0.f,0.f,0.f);
  for (int e = rs; e < re; ++e){
    int s = csr_src[e];
    float a = __expf(lrelu(es[s*4 + hh] + ed_h) - m_h) * inv_h;
    float4 hv = *(const float4*)(h + (size_t)s*HC + (lane<<2));
    acc.x = fmaf(a, hv.x, acc.x);
    acc.y = fmaf(a, hv.y, acc.y);
    acc.z = fmaf(a, hv.z, acc.z);
    acc.w = fmaf(a, hv.w, acc.w);
  }
  *(float4*)(out + (size_t)n*HC + (lane<<2)) = acc;
}

// ---------------- ELU + bias (in place) ----------------
__global__ __launch_bounds__(256) void elu_bias(float* __restrict__ x, const float* __restrict__ b, int total){
  int i = blockIdx.x*256 + threadIdx.x;
  if (i >= total) return;
  float v = x[i] + b[i & (HC-1)];
  x[i] = v > 0.f ? v : expm1f(v);
}

// ---------------- head-mean + b2 + global mean pool (atomic) ----------------
__global__ __launch_bounds__(256) void pool_k(const float* __restrict__ xagg, const float* __restrict__ b2,
                                              const int* __restrict__ batch, float* __restrict__ pooled,
                                              float* __restrict__ cnt){
  int idx = blockIdx.x*256 + threadIdx.x;
  int n = idx >> 6, c = idx & 63;
  if (n >= N_NODES) return;
  const float* r = xagg + (size_t)n*HC;
  float v = 0.25f*(r[c] + r[64+c] + r[128+c] + r[192+c]) + b2[c];
  int g = batch[n];
  unsafeAtomicAdd(pooled + g*HID + c, v);
  if (c == 0) unsafeAtomicAdd(cnt + g, 1.f);
}

// ---------------- MLP head ----------------
__global__ __launch_bounds__(64) void mlp_k(const float* __restrict__ pooled, const float* __restrict__ cnt,
                                            const float* __restrict__ mW1, const float* __restrict__ mb1,
                                            const float* __restrict__ mW2, const float* __restrict__ mb2,
                                            float* __restrict__ out){
  __shared__ float p[HID], h1[HID];
  int g = blockIdx.x, j = threadIdx.x;
  float c = fmaxf(cnt[g], 1.f);
  p[j] = pooled[g*HID + j] / c;
  __syncthreads();
  float acc = mb1[j];
  #pragma unroll 8
  for (int k = 0; k < HID; k++) acc = fmaf(p[k], mW1[k*HID + j], acc);
  h1[j] = fmaxf(acc, 0.f);
  __syncthreads();
  if (j < OUT_DIM){
    float a2 = mb2[j];
    #pragma unroll 8
    for (int k = 0; k < HID; k++) a2 = fmaf(h1[k], mW2[k*OUT_DIM + j], a2);
    out[g*OUT_DIM + j] = a2;
  }
}

extern "C" void kernel_launch(void* const* d_in, const int* in_sizes, int n_in,
                              void* d_out, int out_size, void* d_ws, size_t ws_size,
                              hipStream_t stream){
  const float* imgs  = (const float*)d_in[0];
  const int*   ei    = (const int*)d_in[1];
  const int*   batch = (const int*)d_in[2];
  const float* W_agg = (const float*)d_in[3];
  const float* b_agg = (const float*)d_in[4];
  const float* W0 = (const float*)d_in[5];
  const float* as0 = (const float*)d_in[6];
  const float* ad0 = (const float*)d_in[7];
  const float* b0 = (const float*)d_in[8];
  const float* W1 = (const float*)d_in[9];
  const float* as1 = (const float*)d_in[10];
  const float* ad1 = (const float*)d_in[11];
  const float* b1 = (const float*)d_in[12];
  const float* W2 = (const float*)d_in[13];
  const float* as2 = (const float*)d_in[14];
  const float* ad2 = (const float*)d_in[15];
  const float* b2 = (const float*)d_in[16];
  const float* mW1 = (const float*)d_in[17];
  const float* mb1 = (const float*)d_in[18];
  const float* mW2 = (const float*)d_in[19];
  const float* mb2 = (const float*)d_in[20];
  float* out = (float*)d_out;

  // workspace layout (floats first, 16B-aligned chunks; ~111 MB total)
  float* bufA = (float*)d_ws;                                 // N*256
  float* bufB = bufA + (size_t)N_NODES*HC;                    // N*256
  float* es   = bufB + (size_t)N_NODES*HC;                    // N*4
  float* ed   = es + (size_t)N_NODES*HEADS;                   // N*4
  float* pooled = ed + (size_t)N_NODES*HEADS;                 // 64*64
  float* cnt  = pooled + N_GRAPHS*HID;                        // 64
  int* row_start = (int*)(cnt + N_GRAPHS);                    // N+1
  int* cursor    = row_start + (N_NODES+1);                   // N
  int* csr_src   = cursor + N_NODES;                          // E_TOT

  const int EB = (E_TOT + 255)/256;

  // CSR build (by dst), every call (no cross-call state allowed)
  hipMemsetAsync(cursor, 0, N_NODES*sizeof(int), stream);
  hist_k<<<EB, 256, 0, stream>>>(ei, cursor);
  scan_k<<<1, 1024, 0, stream>>>(cursor, row_start, N_NODES);
  scatter_k<<<EB, 256, 0, stream>>>(ei, cursor, csr_src);

  // aggregator linear
  agg_lin<<<(N_NODES+3)/4, 256, 0, stream>>>(imgs, W_agg, b_agg, bufA);

  const int LB = (N_NODES + 31)/32;
  const int GB = (N_NODES + 3)/4;
  const int XB = ((size_t)N_NODES*HC + 255)/256;

  // layer 0 (K=64)
  lin_k<64><<<LB, 256, 0, stream>>>(bufA, W0, bufB);
  scores_k<<<N_NODES, 256, 0, stream>>>(bufB, as0, ad0, es, ed);
  gat_agg<<<GB, 256, 0, stream>>>(bufB, es, ed, row_start, csr_src, bufA);
  elu_bias<<<XB, 256, 0, stream>>>(bufA, b0, N_NODES*HC);

  // layer 1 (K=256)
  lin_k<256><<<LB, 256, 0, stream>>>(bufA, W1, bufB);
  scores_k<<<N_NODES, 256, 0, stream>>>(bufB, as1, ad1, es, ed);
  gat_agg<<<GB, 256, 0, stream>>>(bufB, es, ed, row_start, csr_src, bufA);
  elu_bias<<<XB, 256, 0, stream>>>(bufA, b1, N_NODES*HC);

  // layer 2 (K=256, mean over heads folded into pool)
  lin_k<256><<<LB, 256, 0, stream>>>(bufA, W2, bufB);
  scores_k<<<N_NODES, 256, 0, stream>>>(bufB, as2, ad2, es, ed);
  gat_agg<<<GB, 256, 0, stream>>>(bufB, es, ed, row_start, csr_src, bufA);

  // pool + MLP
  hipMemsetAsync(pooled, 0, (N_GRAPHS*HID + N_GRAPHS)*sizeof(float), stream);
  pool_k<<<((size_t)N_NODES*HID + 255)/256, 256, 0, stream>>>(bufA, b2, batch, pooled, cnt);
  mlp_k<<<N_GRAPHS, 64, 0, stream>>>(pooled, cnt, mW1, mb1, mW2, mb2, out);
}

// Round 2
// 1452.009 us; speedup vs baseline: 1.2582x; 1.2582x over previous
//
#include <hip/hip_runtime.h>

#define N_NODES 50000
#define N_EDGESX 1600000
#define E_TOT   (N_EDGESX + N_NODES)
#define IN_DIM 128
#define HID 64
#define HEADS 4
#define HC 256
#define N_GRAPHS 64
#define OUT_DIM 10
#define NEG_SLOPE 0.2f

__device__ __forceinline__ float lrelu(float x){ return x > 0.f ? x : NEG_SLOPE*x; }
__device__ __forceinline__ float sel4(float4 v, int i){
  float r = v.x;
  r = (i==1) ? v.y : r;
  r = (i==2) ? v.z : r;
  r = (i==3) ? v.w : r;
  return r;
}

// ---------------- CSR build ----------------
__global__ __launch_bounds__(256) void hist_k(const int* __restrict__ ei, int* __restrict__ cnts){
  int e = blockIdx.x*256 + threadIdx.x;
  if (e >= E_TOT) return;
  int dst = (e < N_EDGESX) ? ei[N_EDGESX + e] : (e - N_EDGESX);
  atomicAdd(&cnts[dst], 1);
}

__global__ __launch_bounds__(1024) void scan_k(int* __restrict__ cnts, int* __restrict__ row_start, int N){
  __shared__ int tmp[1024];
  __shared__ int carry;
  if (threadIdx.x == 0) carry = 0;
  __syncthreads();
  for (int base = 0; base < N; base += 1024){
    int i = base + threadIdx.x;
    int v = (i < N) ? cnts[i] : 0;
    tmp[threadIdx.x] = v;
    __syncthreads();
    for (int off = 1; off < 1024; off <<= 1){
      int t = (threadIdx.x >= (unsigned)off) ? tmp[threadIdx.x - off] : 0;
      __syncthreads();
      tmp[threadIdx.x] += t;
      __syncthreads();
    }
    int excl = tmp[threadIdx.x] - v + carry;
    if (i < N){ row_start[i] = excl; cnts[i] = excl; }
    __syncthreads();
    if (threadIdx.x == 1023) carry += tmp[1023];
    __syncthreads();
  }
  if (threadIdx.x == 0) row_start[N] = carry;
}

__global__ __launch_bounds__(256) void scatter_k(const int* __restrict__ ei, int* __restrict__ cursor,
                                                 int* __restrict__ csr_src){
  int e = blockIdx.x*256 + threadIdx.x;
  if (e >= E_TOT) return;
  int src, dst;
  if (e < N_EDGESX){ src = ei[e]; dst = ei[N_EDGESX + e]; }
  else { src = e - N_EDGESX; dst = src; }
  int pos = atomicAdd(&cursor[dst], 1);
  csr_src[pos] = src;
}

// ---------------- aggregator linear: x0 = imgs @ W_agg + b_agg  [N,64] ----------------
__global__ __launch_bounds__(256) void agg_lin(const float* __restrict__ imgs, const float* __restrict__ W,
                                               const float* __restrict__ b, float* __restrict__ x0){
  __shared__ __align__(16) float xr[4][IN_DIM];
  int w = threadIdx.x >> 6, lane = threadIdx.x & 63;
  int n = blockIdx.x*4 + w;
  if (n >= N_NODES) return;
  ((float2*)xr[w])[lane] = ((const float2*)(imgs + (size_t)n*IN_DIM))[lane];
  float acc = b[lane];
  #pragma unroll 8
  for (int k = 0; k < IN_DIM; k++)
    acc = fmaf(xr[w][k], W[k*HID + lane], acc);
  x0[(size_t)n*HID + lane] = acc;
}

// ---------------- GAT linear: h = x @ W   [N,K] x [K,256] -> [N,256] ----------------
template<int K>
__global__ __launch_bounds__(256) void lin_k(const float* __restrict__ x, const float* __restrict__ W,
                                             float* __restrict__ h){
  __shared__ __align__(16) float xs[K][36];
  const int tid = threadIdx.x;
  const int cg = tid & 63;   // column group: cols cg*4..cg*4+3
  const int ng = tid >> 6;   // node group: nodes ng*8..ng*8+7 (== wave id)
  const int n0 = blockIdx.x * 32;
  for (int idx = tid; idx < 32*K; idx += 256){
    int r = idx / K, c = idx % K;
    int n = n0 + r;
    xs[c][r] = (n < N_NODES) ? x[(size_t)n*K + c] : 0.f;
  }
  __syncthreads();
  float acc[8][4];
  #pragma unroll
  for (int i = 0; i < 8; i++){
    acc[i][0]=0.f; acc[i][1]=0.f; acc[i][2]=0.f; acc[i][3]=0.f;
  }
  #pragma unroll 4
  for (int k = 0; k < K; k++){
    float4 wv = *(const float4*)(W + k*HC + cg*4);
    float4 a0 = *(const float4*)(&xs[k][ng*8]);
    float4 a1 = *(const float4*)(&xs[k][ng*8+4]);
    float xr[8] = {a0.x,a0.y,a0.z,a0.w,a1.x,a1.y,a1.z,a1.w};
    #pragma unroll
    for (int i = 0; i < 8; i++){
      acc[i][0] = fmaf(xr[i], wv.x, acc[i][0]);
      acc[i][1] = fmaf(xr[i], wv.y, acc[i][1]);
      acc[i][2] = fmaf(xr[i], wv.z, acc[i][2]);
      acc[i][3] = fmaf(xr[i], wv.w, acc[i][3]);
    }
  }
  #pragma unroll
  for (int i = 0; i < 8; i++){
    int n = n0 + ng*8 + i;
    if (n < N_NODES){
      float4 o; o.x=acc[i][0]; o.y=acc[i][1]; o.z=acc[i][2]; o.w=acc[i][3];
      *(float4*)(h + (size_t)n*HC + cg*4) = o;
    }
  }
}

// ---------------- per-node attention scores ----------------
__global__ __launch_bounds__(256) void scores_k(const float* __restrict__ h, const float* __restrict__ as,
                                                const float* __restrict__ ad, float* __restrict__ es,
                                                float* __restrict__ ed){
  int n = blockIdx.x;
  int lane = threadIdx.x & 63;
  int head = threadIdx.x >> 6;
  float v = h[(size_t)n*HC + head*HID + lane];
  float ps = v * as[head*HID + lane];
  float pd = v * ad[head*HID + lane];
  #pragma unroll
  for (int off = 32; off >= 1; off >>= 1){
    ps += __shfl_xor(ps, off);
    pd += __shfl_xor(pd, off);
  }
  if (lane == 0){ es[n*4 + head] = ps; ed[n*4 + head] = pd; }
}

// ---------------- GAT aggregation: one wave per dst node, CSR gather ----------------
__global__ __launch_bounds__(256) void gat_agg(const float* __restrict__ h, const float* __restrict__ es,
    const float* __restrict__ ed, const int* __restrict__ row_start, const int* __restrict__ csr_src,
    float* __restrict__ out){
  int lane = threadIdx.x & 63;
  int n = blockIdx.x*4 + (threadIdx.x >> 6);
  if (n >= N_NODES) return;
  int rs = row_start[n], re = row_start[n+1];
  float4 edn = *(const float4*)(ed + n*4);
  // phase 1: segment max (strided over lanes, then butterfly)
  float4 mx = make_float4(-1e30f,-1e30f,-1e30f,-1e30f);
  for (int e = rs + lane; e < re; e += 64){
    int s = csr_src[e];
    float4 e4 = *(const float4*)(es + s*4);
    mx.x = fmaxf(mx.x, lrelu(e4.x + edn.x));
    mx.y = fmaxf(mx.y, lrelu(e4.y + edn.y));
    mx.z = fmaxf(mx.z, lrelu(e4.z + edn.z));
    mx.w = fmaxf(mx.w, lrelu(e4.w + edn.w));
  }
  #pragma unroll
  for (int off = 32; off >= 1; off >>= 1){
    mx.x = fmaxf(mx.x, __shfl_xor(mx.x, off));
    mx.y = fmaxf(mx.y, __shfl_xor(mx.y, off));
    mx.z = fmaxf(mx.z, __shfl_xor(mx.z, off));
    mx.w = fmaxf(mx.w, __shfl_xor(mx.w, off));
  }
  // phase 2: segment sum of exp
  float4 sm = make_float4(0.f,0.f,0.f,0.f);
  for (int e = rs + lane; e < re; e += 64){
    int s = csr_src[e];
    float4 e4 = *(const float4*)(es + s*4);
    sm.x += __expf(lrelu(e4.x + edn.x) - mx.x);
    sm.y += __expf(lrelu(e4.y + edn.y) - mx.y);
    sm.z += __expf(lrelu(e4.z + edn.z) - mx.z);
    sm.w += __expf(lrelu(e4.w + edn.w) - mx.w);
  }
  #pragma unroll
  for (int off = 32; off >= 1; off >>= 1){
    sm.x += __shfl_xor(sm.x, off);
    sm.y += __shfl_xor(sm.y, off);
    sm.z += __shfl_xor(sm.z, off);
    sm.w += __shfl_xor(sm.w, off);
  }
  // phase 3: weighted feature gather; lane owns 4 contiguous feature dims (one head)
  int hh = lane >> 4;
  float m_h  = sel4(mx, hh);
  float ed_h = sel4(edn, hh);
  float inv_h = 1.f / (sel4(sm, hh) + 1e-16f);
  float4 acc = make_float4(0.f,0.f,0.f,0.f);
  for (int e = rs; e < re; ++e){
    int s = csr_src[e];
    float a = __expf(lrelu(es[s*4 + hh] + ed_h) - m_h) * inv_h;
    float4 hv = *(const float4*)(h + (size_t)s*HC + (lane<<2));
    acc.x = fmaf(a, hv.x, acc.x);
    acc.y = fmaf(a, hv.y, acc.y);
    acc.z = fmaf(a, hv.z, acc.z);
    acc.w = fmaf(a, hv.w, acc.w);
  }
  *(float4*)(out + (size_t)n*HC + (lane<<2)) = acc;
}

// ---------------- ELU + bias (in place) ----------------
__global__ __launch_bounds__(256) void elu_bias(float* __restrict__ x, const float* __restrict__ b, int total){
  int i = blockIdx.x*256 + threadIdx.x;
  if (i >= total) return;
  float v = x[i] + b[i & (HC-1)];
  x[i] = v > 0.f ? v : expm1f(v);
}

// ---------------- head-mean + global mean pool (sorted-batch register accumulate) ----------------
// batch is sorted -> each thread accumulates its channel partial in a register and
// flushes one atomic per graph-transition (~130K atomics total vs 3.2M before).
#define PB_NODES 128
__global__ __launch_bounds__(256) void pool_k(const float* __restrict__ xagg,
                                              const int* __restrict__ batch, float* __restrict__ pooled,
                                              float* __restrict__ cnt){
  int c = threadIdx.x & 63;
  int sub = threadIdx.x >> 6;           // 0..3
  int n0 = blockIdx.x * PB_NODES;
  int nend = n0 + PB_NODES; if (nend > N_NODES) nend = N_NODES;
  float acc = 0.f; int curg = -1; int cl = 0;
  for (int n = n0 + sub; n < nend; n += 4){
    int g = batch[n];
    if (g != curg){
      if (curg >= 0){
        unsafeAtomicAdd(pooled + curg*HID + c, acc);
        if (c == 0) unsafeAtomicAdd(cnt + curg, (float)cl);
      }
      curg = g; acc = 0.f; cl = 0;
    }
    const float* r = xagg + (size_t)n*HC;
    acc += 0.25f*(r[c] + r[64+c] + r[128+c] + r[192+c]);
    cl++;
  }
  if (curg >= 0){
    unsafeAtomicAdd(pooled + curg*HID + c, acc);
    if (c == 0) unsafeAtomicAdd(cnt + curg, (float)cl);
  }
}

// ---------------- MLP head (b2 folded in: mean(x+b2) = mean(x)+b2) ----------------
__global__ __launch_bounds__(64) void mlp_k(const float* __restrict__ pooled, const float* __restrict__ cnt,
                                            const float* __restrict__ b2,
                                            const float* __restrict__ mW1, const float* __restrict__ mb1,
                                            const float* __restrict__ mW2, const float* __restrict__ mb2,
                                            float* __restrict__ out){
  __shared__ float p[HID], h1[HID];
  int g = blockIdx.x, j = threadIdx.x;
  float c = fmaxf(cnt[g], 1.f);
  p[j] = pooled[g*HID + j] / c + b2[j];
  __syncthreads();
  float acc = mb1[j];
  #pragma unroll 8
  for (int k = 0; k < HID; k++) acc = fmaf(p[k], mW1[k*HID + j], acc);
  h1[j] = fmaxf(acc, 0.f);
  __syncthreads();
  if (j < OUT_DIM){
    float a2 = mb2[j];
    #pragma unroll 8
    for (int k = 0; k < HID; k++) a2 = fmaf(h1[k], mW2[k*OUT_DIM + j], a2);
    out[g*OUT_DIM + j] = a2;
  }
}

extern "C" void kernel_launch(void* const* d_in, const int* in_sizes, int n_in,
                              void* d_out, int out_size, void* d_ws, size_t ws_size,
                              hipStream_t stream){
  const float* imgs  = (const float*)d_in[0];
  const int*   ei    = (const int*)d_in[1];
  const int*   batch = (const int*)d_in[2];
  const float* W_agg = (const float*)d_in[3];
  const float* b_agg = (const float*)d_in[4];
  const float* W0 = (const float*)d_in[5];
  const float* as0 = (const float*)d_in[6];
  const float* ad0 = (const float*)d_in[7];
  const float* b0 = (const float*)d_in[8];
  const float* W1 = (const float*)d_in[9];
  const float* as1 = (const float*)d_in[10];
  const float* ad1 = (const float*)d_in[11];
  const float* b1 = (const float*)d_in[12];
  const float* W2 = (const float*)d_in[13];
  const float* as2 = (const float*)d_in[14];
  const float* ad2 = (const float*)d_in[15];
  const float* b2 = (const float*)d_in[16];
  const float* mW1 = (const float*)d_in[17];
  const float* mb1 = (const float*)d_in[18];
  const float* mW2 = (const float*)d_in[19];
  const float* mb2 = (const float*)d_in[20];
  float* out = (float*)d_out;

  // workspace layout (floats first, 16B-aligned chunks; ~111 MB total)
  float* bufA = (float*)d_ws;                                 // N*256
  float* bufB = bufA + (size_t)N_NODES*HC;                    // N*256
  float* es   = bufB + (size_t)N_NODES*HC;                    // N*4
  float* ed   = es + (size_t)N_NODES*HEADS;                   // N*4
  float* pooled = ed + (size_t)N_NODES*HEADS;                 // 64*64
  float* cnt  = pooled + N_GRAPHS*HID;                        // 64
  int* row_start = (int*)(cnt + N_GRAPHS);                    // N+1
  int* cursor    = row_start + (N_NODES+1);                   // N
  int* csr_src   = cursor + N_NODES;                          // E_TOT

  const int EB = (E_TOT + 255)/256;

  // CSR build (by dst), every call (no cross-call state allowed)
  hipMemsetAsync(cursor, 0, N_NODES*sizeof(int), stream);
  hist_k<<<EB, 256, 0, stream>>>(ei, cursor);
  scan_k<<<1, 1024, 0, stream>>>(cursor, row_start, N_NODES);
  scatter_k<<<EB, 256, 0, stream>>>(ei, cursor, csr_src);

  // aggregator linear
  agg_lin<<<(N_NODES+3)/4, 256, 0, stream>>>(imgs, W_agg, b_agg, bufA);

  const int LB = (N_NODES + 31)/32;
  const int GB = (N_NODES + 3)/4;
  const int XB = ((size_t)N_NODES*HC + 255)/256;

  // layer 0 (K=64)
  lin_k<64><<<LB, 256, 0, stream>>>(bufA, W0, bufB);
  scores_k<<<N_NODES, 256, 0, stream>>>(bufB, as0, ad0, es, ed);
  gat_agg<<<GB, 256, 0, stream>>>(bufB, es, ed, row_start, csr_src, bufA);
  elu_bias<<<XB, 256, 0, stream>>>(bufA, b0, N_NODES*HC);

  // layer 1 (K=256)
  lin_k<256><<<LB, 256, 0, stream>>>(bufA, W1, bufB);
  scores_k<<<N_NODES, 256, 0, stream>>>(bufB, as1, ad1, es, ed);
  gat_agg<<<GB, 256, 0, stream>>>(bufB, es, ed, row_start, csr_src, bufA);
  elu_bias<<<XB, 256, 0, stream>>>(bufA, b1, N_NODES*HC);

  // layer 2 (K=256, mean over heads folded into pool)
  lin_k<256><<<LB, 256, 0, stream>>>(bufA, W2, bufB);
  scores_k<<<N_NODES, 256, 0, stream>>>(bufB, as2, ad2, es, ed);
  gat_agg<<<GB, 256, 0, stream>>>(bufB, es, ed, row_start, csr_src, bufA);

  // pool + MLP
  hipMemsetAsync(pooled, 0, (N_GRAPHS*HID + N_GRAPHS)*sizeof(float), stream);
  pool_k<<<(N_NODES + PB_NODES - 1)/PB_NODES, 256, 0, stream>>>(bufA, batch, pooled, cnt);
  mlp_k<<<N_GRAPHS, 64, 0, stream>>>(pooled, cnt, b2, mW1, mb1, mW2, mb2, out);
}

// Round 3
// 1152.960 us; speedup vs baseline: 1.5846x; 1.2594x over previous
//
#include <hip/hip_runtime.h>
#include <hip/hip_bf16.h>

#define N_NODES 50000
#define N_EDGESX 1600000
#define E_TOT   (N_EDGESX + N_NODES)
#define IN_DIM 128
#define HID 64
#define HEADS 4
#define HC 256
#define N_GRAPHS 64
#define OUT_DIM 10
#define NEG_SLOPE 0.2f

__device__ __forceinline__ float lrelu(float x){ return x > 0.f ? x : NEG_SLOPE*x; }
__device__ __forceinline__ float sel4(float4 v, int i){
  float r = v.x;
  r = (i==1) ? v.y : r;
  r = (i==2) ? v.z : r;
  r = (i==3) ? v.w : r;
  return r;
}
__device__ __forceinline__ unsigned short f2bf(float f){
  union { __hip_bfloat16 b; unsigned short u; } cv;
  cv.b = __float2bfloat16(f);
  return cv.u;
}
__device__ __forceinline__ float bf2f(unsigned short u){
  return __uint_as_float(((unsigned int)u) << 16);
}

// ---------------- CSR build ----------------
__global__ __launch_bounds__(256) void hist_k(const int* __restrict__ ei, int* __restrict__ cnts){
  int e = blockIdx.x*256 + threadIdx.x;
  if (e >= E_TOT) return;
  int dst = (e < N_EDGESX) ? ei[N_EDGESX + e] : (e - N_EDGESX);
  atomicAdd(&cnts[dst], 1);
}

// multi-block scan: scan1 (per-256-chunk excl scan + block totals), scan2 (scan totals), scan3 (combine)
__global__ __launch_bounds__(256) void scan1_k(const int* __restrict__ cnts, int* __restrict__ excl,
                                               int* __restrict__ partials){
  __shared__ int tmp[256];
  int i = blockIdx.x*256 + threadIdx.x;
  int v = (i < N_NODES) ? cnts[i] : 0;
  tmp[threadIdx.x] = v;
  __syncthreads();
  for (int off = 1; off < 256; off <<= 1){
    int t = (threadIdx.x >= (unsigned)off) ? tmp[threadIdx.x - off] : 0;
    __syncthreads();
    tmp[threadIdx.x] += t;
    __syncthreads();
  }
  if (i < N_NODES) excl[i] = tmp[threadIdx.x] - v;
  if (threadIdx.x == 255) partials[blockIdx.x] = tmp[255];
}

__global__ __launch_bounds__(256) void scan2_k(int* __restrict__ partials, int nb){
  __shared__ int tmp[256];
  int v = (threadIdx.x < nb) ? partials[threadIdx.x] : 0;
  tmp[threadIdx.x] = v;
  __syncthreads();
  for (int off = 1; off < 256; off <<= 1){
    int t = (threadIdx.x >= (unsigned)off) ? tmp[threadIdx.x - off] : 0;
    __syncthreads();
    tmp[threadIdx.x] += t;
    __syncthreads();
  }
  if (threadIdx.x < nb) partials[threadIdx.x] = tmp[threadIdx.x] - v;
}

__global__ __launch_bounds__(256) void scan3_k(const int* __restrict__ excl, const int* __restrict__ partials,
                                               int* __restrict__ row_start, int* __restrict__ cursor){
  int i = blockIdx.x*256 + threadIdx.x;
  if (i >= N_NODES) return;
  int r = excl[i] + partials[blockIdx.x];
  row_start[i] = r;
  cursor[i] = r;
  if (i == 0) row_start[N_NODES] = E_TOT;
}

__global__ __launch_bounds__(256) void scatter_k(const int* __restrict__ ei, int* __restrict__ cursor,
                                                 int* __restrict__ csr_src){
  int e = blockIdx.x*256 + threadIdx.x;
  if (e >= E_TOT) return;
  int src, dst;
  if (e < N_EDGESX){ src = ei[e]; dst = ei[N_EDGESX + e]; }
  else { src = e - N_EDGESX; dst = src; }
  int pos = atomicAdd(&cursor[dst], 1);
  csr_src[pos] = src;
}

// ---------------- aggregator linear: x0 = imgs @ W_agg + b_agg  [N,64] f32 ----------------
__global__ __launch_bounds__(256) void agg_lin(const float* __restrict__ imgs, const float* __restrict__ W,
                                               const float* __restrict__ b, float* __restrict__ x0){
  __shared__ __align__(16) float xr[4][IN_DIM];
  int w = threadIdx.x >> 6, lane = threadIdx.x & 63;
  int n = blockIdx.x*4 + w;
  if (n >= N_NODES) return;
  ((float2*)xr[w])[lane] = ((const float2*)(imgs + (size_t)n*IN_DIM))[lane];
  float acc = b[lane];
  #pragma unroll 8
  for (int k = 0; k < IN_DIM; k++)
    acc = fmaf(xr[w][k], W[k*HID + lane], acc);
  x0[(size_t)n*HID + lane] = acc;
}

// ---------------- GAT linear: h = x @ W   [N,K] f32 x [K,256] f32 -> [N,256] bf16 ----------------
template<int K>
__global__ __launch_bounds__(256) void lin_k(const float* __restrict__ x, const float* __restrict__ W,
                                             unsigned short* __restrict__ h){
  __shared__ __align__(16) float xs[K][36];
  const int tid = threadIdx.x;
  const int cg = tid & 63;   // column group: cols cg*4..cg*4+3
  const int ng = tid >> 6;   // node group: nodes ng*8..ng*8+7 (== wave id)
  const int n0 = blockIdx.x * 32;
  for (int idx = tid; idx < 32*K; idx += 256){
    int r = idx / K, c = idx % K;
    int n = n0 + r;
    xs[c][r] = (n < N_NODES) ? x[(size_t)n*K + c] : 0.f;
  }
  __syncthreads();
  float acc[8][4];
  #pragma unroll
  for (int i = 0; i < 8; i++){
    acc[i][0]=0.f; acc[i][1]=0.f; acc[i][2]=0.f; acc[i][3]=0.f;
  }
  #pragma unroll 4
  for (int k = 0; k < K; k++){
    float4 wv = *(const float4*)(W + k*HC + cg*4);
    float4 a0 = *(const float4*)(&xs[k][ng*8]);
    float4 a1 = *(const float4*)(&xs[k][ng*8+4]);
    float xr[8] = {a0.x,a0.y,a0.z,a0.w,a1.x,a1.y,a1.z,a1.w};
    #pragma unroll
    for (int i = 0; i < 8; i++){
      acc[i][0] = fmaf(xr[i], wv.x, acc[i][0]);
      acc[i][1] = fmaf(xr[i], wv.y, acc[i][1]);
      acc[i][2] = fmaf(xr[i], wv.z, acc[i][2]);
      acc[i][3] = fmaf(xr[i], wv.w, acc[i][3]);
    }
  }
  #pragma unroll
  for (int i = 0; i < 8; i++){
    int n = n0 + ng*8 + i;
    if (n < N_NODES){
      ushort4 o;
      o.x = f2bf(acc[i][0]); o.y = f2bf(acc[i][1]);
      o.z = f2bf(acc[i][2]); o.w = f2bf(acc[i][3]);
      *(ushort4*)(h + (size_t)n*HC + cg*4) = o;
    }
  }
}

// ---------------- per-node attention scores (reads bf16 h) ----------------
__global__ __launch_bounds__(256) void scores_k(const unsigned short* __restrict__ h, const float* __restrict__ as,
                                                const float* __restrict__ ad, float* __restrict__ es,
                                                float* __restrict__ ed){
  int n = blockIdx.x;
  int lane = threadIdx.x & 63;
  int head = threadIdx.x >> 6;
  float v = bf2f(h[(size_t)n*HC + threadIdx.x]);
  float ps = v * as[threadIdx.x];   // as/ad are [HEADS][HID] flat == [256]
  float pd = v * ad[threadIdx.x];
  #pragma unroll
  for (int off = 32; off >= 1; off >>= 1){
    ps += __shfl_xor(ps, off);
    pd += __shfl_xor(pd, off);
  }
  if (lane == 0){ es[n*4 + head] = ps; ed[n*4 + head] = pd; }
}

// ---------------- GAT aggregation: one wave per dst node, bf16 CSR gather, fused bias+ELU ----------------
template<int ACT>
__global__ __launch_bounds__(256) void gat_agg(const unsigned short* __restrict__ h, const float* __restrict__ es,
    const float* __restrict__ ed, const int* __restrict__ row_start, const int* __restrict__ csr_src,
    const float* __restrict__ bias, float* __restrict__ out){
  int lane = threadIdx.x & 63;
  int n = blockIdx.x*4 + (threadIdx.x >> 6);
  if (n >= N_NODES) return;
  int rs = row_start[n], re = row_start[n+1];
  float4 edn = *(const float4*)(ed + n*4);
  // phase 1: segment max (strided over lanes, then butterfly)
  float4 mx = make_float4(-1e30f,-1e30f,-1e30f,-1e30f);
  for (int e = rs + lane; e < re; e += 64){
    int s = csr_src[e];
    float4 e4 = *(const float4*)(es + s*4);
    mx.x = fmaxf(mx.x, lrelu(e4.x + edn.x));
    mx.y = fmaxf(mx.y, lrelu(e4.y + edn.y));
    mx.z = fmaxf(mx.z, lrelu(e4.z + edn.z));
    mx.w = fmaxf(mx.w, lrelu(e4.w + edn.w));
  }
  #pragma unroll
  for (int off = 32; off >= 1; off >>= 1){
    mx.x = fmaxf(mx.x, __shfl_xor(mx.x, off));
    mx.y = fmaxf(mx.y, __shfl_xor(mx.y, off));
    mx.z = fmaxf(mx.z, __shfl_xor(mx.z, off));
    mx.w = fmaxf(mx.w, __shfl_xor(mx.w, off));
  }
  // phase 2: segment sum of exp
  float4 sm = make_float4(0.f,0.f,0.f,0.f);
  for (int e = rs + lane; e < re; e += 64){
    int s = csr_src[e];
    float4 e4 = *(const float4*)(es + s*4);
    sm.x += __expf(lrelu(e4.x + edn.x) - mx.x);
    sm.y += __expf(lrelu(e4.y + edn.y) - mx.y);
    sm.z += __expf(lrelu(e4.z + edn.z) - mx.z);
    sm.w += __expf(lrelu(e4.w + edn.w) - mx.w);
  }
  #pragma unroll
  for (int off = 32; off >= 1; off >>= 1){
    sm.x += __shfl_xor(sm.x, off);
    sm.y += __shfl_xor(sm.y, off);
    sm.z += __shfl_xor(sm.z, off);
    sm.w += __shfl_xor(sm.w, off);
  }
  // phase 3: weighted bf16 feature gather; lane owns 4 contiguous feature dims (one head)
  int hh = lane >> 4;
  float m_h  = sel4(mx, hh);
  float ed_h = sel4(edn, hh);
  float inv_h = 1.f / (sel4(sm, hh) + 1e-16f);
  float4 acc = make_float4(0.f,0.f,0.f,0.f);
  for (int e = rs; e < re; ++e){
    int s = csr_src[e];
    float a = __expf(lrelu(es[s*4 + hh] + ed_h) - m_h) * inv_h;
    ushort4 hv = *(const ushort4*)(h + (size_t)s*HC + (lane<<2));
    acc.x = fmaf(a, bf2f(hv.x), acc.x);
    acc.y = fmaf(a, bf2f(hv.y), acc.y);
    acc.z = fmaf(a, bf2f(hv.z), acc.z);
    acc.w = fmaf(a, bf2f(hv.w), acc.w);
  }
  if (ACT){
    float4 b4 = *(const float4*)(bias + (lane<<2));
    acc.x += b4.x; acc.y += b4.y; acc.z += b4.z; acc.w += b4.w;
    acc.x = acc.x > 0.f ? acc.x : expm1f(acc.x);
    acc.y = acc.y > 0.f ? acc.y : expm1f(acc.y);
    acc.z = acc.z > 0.f ? acc.z : expm1f(acc.z);
    acc.w = acc.w > 0.f ? acc.w : expm1f(acc.w);
  }
  *(float4*)(out + (size_t)n*HC + (lane<<2)) = acc;
}

// ---------------- head-mean + global mean pool (sorted-batch register accumulate) ----------------
#define PB_NODES 128
__global__ __launch_bounds__(256) void pool_k(const float* __restrict__ xagg,
                                              const int* __restrict__ batch, float* __restrict__ pooled,
                                              float* __restrict__ cnt){
  int c = threadIdx.x & 63;
  int sub = threadIdx.x >> 6;           // 0..3
  int n0 = blockIdx.x * PB_NODES;
  int nend = n0 + PB_NODES; if (nend > N_NODES) nend = N_NODES;
  float acc = 0.f; int curg = -1; int cl = 0;
  for (int n = n0 + sub; n < nend; n += 4){
    int g = batch[n];
    if (g != curg){
      if (curg >= 0){
        unsafeAtomicAdd(pooled + curg*HID + c, acc);
        if (c == 0) unsafeAtomicAdd(cnt + curg, (float)cl);
      }
      curg = g; acc = 0.f; cl = 0;
    }
    const float* r = xagg + (size_t)n*HC;
    acc += 0.25f*(r[c] + r[64+c] + r[128+c] + r[192+c]);
    cl++;
  }
  if (curg >= 0){
    unsafeAtomicAdd(pooled + curg*HID + c, acc);
    if (c == 0) unsafeAtomicAdd(cnt + curg, (float)cl);
  }
}

// ---------------- MLP head (b2 folded in: mean(x+b2) = mean(x)+b2) ----------------
__global__ __launch_bounds__(64) void mlp_k(const float* __restrict__ pooled, const float* __restrict__ cnt,
                                            const float* __restrict__ b2,
                                            const float* __restrict__ mW1, const float* __restrict__ mb1,
                                            const float* __restrict__ mW2, const float* __restrict__ mb2,
                                            float* __restrict__ out){
  __shared__ float p[HID], h1[HID];
  int g = blockIdx.x, j = threadIdx.x;
  float c = fmaxf(cnt[g], 1.f);
  p[j] = pooled[g*HID + j] / c + b2[j];
  __syncthreads();
  float acc = mb1[j];
  #pragma unroll 8
  for (int k = 0; k < HID; k++) acc = fmaf(p[k], mW1[k*HID + j], acc);
  h1[j] = fmaxf(acc, 0.f);
  __syncthreads();
  if (j < OUT_DIM){
    float a2 = mb2[j];
    #pragma unroll 8
    for (int k = 0; k < HID; k++) a2 = fmaf(h1[k], mW2[k*OUT_DIM + j], a2);
    out[g*OUT_DIM + j] = a2;
  }
}

extern "C" void kernel_launch(void* const* d_in, const int* in_sizes, int n_in,
                              void* d_out, int out_size, void* d_ws, size_t ws_size,
                              hipStream_t stream){
  const float* imgs  = (const float*)d_in[0];
  const int*   ei    = (const int*)d_in[1];
  const int*   batch = (const int*)d_in[2];
  const float* W_agg = (const float*)d_in[3];
  const float* b_agg = (const float*)d_in[4];
  const float* W0 = (const float*)d_in[5];
  const float* as0 = (const float*)d_in[6];
  const float* ad0 = (const float*)d_in[7];
  const float* b0 = (const float*)d_in[8];
  const float* W1 = (const float*)d_in[9];
  const float* as1 = (const float*)d_in[10];
  const float* ad1 = (const float*)d_in[11];
  const float* b1 = (const float*)d_in[12];
  const float* W2 = (const float*)d_in[13];
  const float* as2 = (const float*)d_in[14];
  const float* ad2 = (const float*)d_in[15];
  const float* b2 = (const float*)d_in[16];
  const float* mW1 = (const float*)d_in[17];
  const float* mb1 = (const float*)d_in[18];
  const float* mW2 = (const float*)d_in[19];
  const float* mb2 = (const float*)d_in[20];
  float* out = (float*)d_out;

  // workspace layout
  float* bufA = (float*)d_ws;                                 // N*256 f32 (x / agg out)
  float* bufBf = bufA + (size_t)N_NODES*HC;                   // region reused as bf16 h
  unsigned short* hb = (unsigned short*)bufBf;                // N*256 bf16
  float* es   = bufBf + (size_t)N_NODES*HC;                   // N*4
  float* ed   = es + (size_t)N_NODES*HEADS;                   // N*4
  float* pooled = ed + (size_t)N_NODES*HEADS;                 // 64*64
  float* cnt  = pooled + N_GRAPHS*HID;                        // 64
  int* row_start = (int*)(cnt + N_GRAPHS);                    // N+1
  int* cursor    = row_start + (N_NODES+1);                   // N
  int* csr_src   = cursor + N_NODES;                          // E_TOT
  int* excl      = csr_src + E_TOT;                           // N
  int* partials  = excl + N_NODES;                            // 256

  const int EB = (E_TOT + 255)/256;
  const int NB = (N_NODES + 255)/256;   // 196

  // CSR build (by dst), every call (no cross-call state allowed)
  hipMemsetAsync(cursor, 0, N_NODES*sizeof(int), stream);
  hist_k<<<EB, 256, 0, stream>>>(ei, cursor);
  scan1_k<<<NB, 256, 0, stream>>>(cursor, excl, partials);
  scan2_k<<<1, 256, 0, stream>>>(partials, NB);
  scan3_k<<<NB, 256, 0, stream>>>(excl, partials, row_start, cursor);
  scatter_k<<<EB, 256, 0, stream>>>(ei, cursor, csr_src);

  // aggregator linear
  agg_lin<<<(N_NODES+3)/4, 256, 0, stream>>>(imgs, W_agg, b_agg, bufA);

  const int LB = (N_NODES + 31)/32;
  const int GB = (N_NODES + 3)/4;

  // layer 0 (K=64)
  lin_k<64><<<LB, 256, 0, stream>>>(bufA, W0, hb);
  scores_k<<<N_NODES, 256, 0, stream>>>(hb, as0, ad0, es, ed);
  gat_agg<1><<<GB, 256, 0, stream>>>(hb, es, ed, row_start, csr_src, b0, bufA);

  // layer 1 (K=256)
  lin_k<256><<<LB, 256, 0, stream>>>(bufA, W1, hb);
  scores_k<<<N_NODES, 256, 0, stream>>>(hb, as1, ad1, es, ed);
  gat_agg<1><<<GB, 256, 0, stream>>>(hb, es, ed, row_start, csr_src, b1, bufA);

  // layer 2 (K=256, bias/head-mean folded into pool/mlp)
  lin_k<256><<<LB, 256, 0, stream>>>(bufA, W2, hb);
  scores_k<<<N_NODES, 256, 0, stream>>>(hb, as2, ad2, es, ed);
  gat_agg<0><<<GB, 256, 0, stream>>>(hb, es, ed, row_start, csr_src, nullptr, bufA);

  // pool + MLP
  hipMemsetAsync(pooled, 0, (N_GRAPHS*HID + N_GRAPHS)*sizeof(float), stream);
  pool_k<<<(N_NODES + PB_NODES - 1)/PB_NODES, 256, 0, stream>>>(bufA, batch, pooled, cnt);
  mlp_k<<<N_GRAPHS, 64, 0, stream>>>(pooled, cnt, b2, mW1, mb1, mW2, mb2, out);
}

// Round 4
// 884.391 us; speedup vs baseline: 2.0658x; 1.3037x over previous
//
#include <hip/hip_runtime.h>
#include <hip/hip_bf16.h>

#define N_NODES 50000
#define N_EDGESX 1600000
#define E_TOT   (N_EDGESX + N_NODES)
#define IN_DIM 128
#define HID 64
#define HEADS 4
#define HC 256
#define N_GRAPHS 64
#define OUT_DIM 10
#define NEG_SLOPE 0.2f

__device__ __forceinline__ float lrelu(float x){ return fmaxf(x, NEG_SLOPE*x); }
__device__ __forceinline__ float sel4(float4 v, int i){
  float r = v.x;
  r = (i==1) ? v.y : r;
  r = (i==2) ? v.z : r;
  r = (i==3) ? v.w : r;
  return r;
}
__device__ __forceinline__ unsigned short f2bf(float f){
  union { __hip_bfloat16 b; unsigned short u; } cv;
  cv.b = __float2bfloat16(f);
  return cv.u;
}
__device__ __forceinline__ float bflo(unsigned int u){ return __uint_as_float(u << 16); }
__device__ __forceinline__ float bfhi(unsigned int u){ return __uint_as_float(u & 0xffff0000u); }

// ---------------- CSR build ----------------
__global__ __launch_bounds__(256) void hist_k(const int* __restrict__ ei, int* __restrict__ cnts){
  int e = blockIdx.x*256 + threadIdx.x;
  if (e >= E_TOT) return;
  int dst = (e < N_EDGESX) ? ei[N_EDGESX + e] : (e - N_EDGESX);
  atomicAdd(&cnts[dst], 1);
}

__global__ __launch_bounds__(256) void scan1_k(const int* __restrict__ cnts, int* __restrict__ excl,
                                               int* __restrict__ partials){
  __shared__ int tmp[256];
  int i = blockIdx.x*256 + threadIdx.x;
  int v = (i < N_NODES) ? cnts[i] : 0;
  tmp[threadIdx.x] = v;
  __syncthreads();
  for (int off = 1; off < 256; off <<= 1){
    int t = (threadIdx.x >= (unsigned)off) ? tmp[threadIdx.x - off] : 0;
    __syncthreads();
    tmp[threadIdx.x] += t;
    __syncthreads();
  }
  if (i < N_NODES) excl[i] = tmp[threadIdx.x] - v;
  if (threadIdx.x == 255) partials[blockIdx.x] = tmp[255];
}

__global__ __launch_bounds__(256) void scan2_k(int* __restrict__ partials, int nb){
  __shared__ int tmp[256];
  int v = (threadIdx.x < nb) ? partials[threadIdx.x] : 0;
  tmp[threadIdx.x] = v;
  __syncthreads();
  for (int off = 1; off < 256; off <<= 1){
    int t = (threadIdx.x >= (unsigned)off) ? tmp[threadIdx.x - off] : 0;
    __syncthreads();
    tmp[threadIdx.x] += t;
    __syncthreads();
  }
  if (threadIdx.x < nb) partials[threadIdx.x] = tmp[threadIdx.x] - v;
}

__global__ __launch_bounds__(256) void scan3_k(const int* __restrict__ excl, const int* __restrict__ partials,
                                               int* __restrict__ row_start, int* __restrict__ cursor){
  int i = blockIdx.x*256 + threadIdx.x;
  if (i >= N_NODES) return;
  int r = excl[i] + partials[blockIdx.x];
  row_start[i] = r;
  cursor[i] = r;
  if (i == 0) row_start[N_NODES] = E_TOT;
}

__global__ __launch_bounds__(256) void scatter_k(const int* __restrict__ ei, int* __restrict__ cursor,
                                                 int* __restrict__ csr_src){
  int e = blockIdx.x*256 + threadIdx.x;
  if (e >= E_TOT) return;
  int src, dst;
  if (e < N_EDGESX){ src = ei[e]; dst = ei[N_EDGESX + e]; }
  else { src = e - N_EDGESX; dst = src; }
  int pos = atomicAdd(&cursor[dst], 1);
  csr_src[pos] = src;
}

// ---------------- aggregator linear: x0 = imgs @ W_agg + b_agg  [N,64] f32 ----------------
__global__ __launch_bounds__(256) void agg_lin(const float* __restrict__ imgs, const float* __restrict__ W,
                                               const float* __restrict__ b, float* __restrict__ x0){
  __shared__ __align__(16) float xr[4][IN_DIM];
  int w = threadIdx.x >> 6, lane = threadIdx.x & 63;
  int n = blockIdx.x*4 + w;
  if (n >= N_NODES) return;
  ((float2*)xr[w])[lane] = ((const float2*)(imgs + (size_t)n*IN_DIM))[lane];
  float acc = b[lane];
  #pragma unroll 8
  for (int k = 0; k < IN_DIM; k++)
    acc = fmaf(xr[w][k], W[k*HID + lane], acc);
  x0[(size_t)n*HID + lane] = acc;
}

// ---------------- GAT linear + fused attention scores ----------------
// h = x @ W -> bf16 [N,256]; es/ed = per-head dots with a_src/a_dst (f32, from f32 acc)
template<int K>
__global__ __launch_bounds__(256) void lin_k(const float* __restrict__ x, const float* __restrict__ W,
                                             const float* __restrict__ as_, const float* __restrict__ ad_,
                                             unsigned short* __restrict__ h,
                                             float* __restrict__ es, float* __restrict__ ed){
  __shared__ __align__(16) float xs[K][36];
  const int tid = threadIdx.x;
  const int cg = tid & 63;   // column group: cols cg*4..cg*4+3 (head = cg>>4)
  const int ng = tid >> 6;   // wave id: nodes ng*8..ng*8+7
  const int n0 = blockIdx.x * 32;
  for (int idx = tid; idx < 32*K; idx += 256){
    int r = idx / K, c = idx % K;
    int n = n0 + r;
    xs[c][r] = (n < N_NODES) ? x[(size_t)n*K + c] : 0.f;
  }
  __syncthreads();
  float acc[8][4];
  #pragma unroll
  for (int i = 0; i < 8; i++){
    acc[i][0]=0.f; acc[i][1]=0.f; acc[i][2]=0.f; acc[i][3]=0.f;
  }
  #pragma unroll 4
  for (int k = 0; k < K; k++){
    float4 wv = *(const float4*)(W + k*HC + cg*4);
    float4 a0 = *(const float4*)(&xs[k][ng*8]);
    float4 a1 = *(const float4*)(&xs[k][ng*8+4]);
    float xr[8] = {a0.x,a0.y,a0.z,a0.w,a1.x,a1.y,a1.z,a1.w};
    #pragma unroll
    for (int i = 0; i < 8; i++){
      acc[i][0] = fmaf(xr[i], wv.x, acc[i][0]);
      acc[i][1] = fmaf(xr[i], wv.y, acc[i][1]);
      acc[i][2] = fmaf(xr[i], wv.z, acc[i][2]);
      acc[i][3] = fmaf(xr[i], wv.w, acc[i][3]);
    }
  }
  // fused scores: per node i, per head (16-lane group): ps = sum over head's 64 cols
  float4 asv = *(const float4*)(as_ + cg*4);
  float4 adv = *(const float4*)(ad_ + cg*4);
  #pragma unroll
  for (int i = 0; i < 8; i++){
    float ps = acc[i][0]*asv.x + acc[i][1]*asv.y + acc[i][2]*asv.z + acc[i][3]*asv.w;
    float pd = acc[i][0]*adv.x + acc[i][1]*adv.y + acc[i][2]*adv.z + acc[i][3]*adv.w;
    #pragma unroll
    for (int off = 8; off >= 1; off >>= 1){
      ps += __shfl_xor(ps, off);
      pd += __shfl_xor(pd, off);
    }
    int n = n0 + ng*8 + i;
    if ((cg & 15) == 0 && n < N_NODES){
      es[n*4 + (cg>>4)] = ps;
      ed[n*4 + (cg>>4)] = pd;
    }
  }
  // bf16 h store
  #pragma unroll
  for (int i = 0; i < 8; i++){
    int n = n0 + ng*8 + i;
    if (n < N_NODES){
      ushort4 o;
      o.x = f2bf(acc[i][0]); o.y = f2bf(acc[i][1]);
      o.z = f2bf(acc[i][2]); o.w = f2bf(acc[i][3]);
      *(ushort4*)(h + (size_t)n*HC + cg*4) = o;
    }
  }
}

// ---------------- GAT aggregation v2: single pass, no segment-max, chunked LDS staging ----------------
// out_n = (sum_e w_e * h_src(e)) / (sum_e w_e),  w_e = exp(lrelu(es[s]+ed[n]))
template<int ACT>
__global__ __launch_bounds__(256) void gat_agg(const unsigned short* __restrict__ h,
    const float* __restrict__ es, const float* __restrict__ ed,
    const int* __restrict__ row_start, const int* __restrict__ csr_src,
    const float* __restrict__ bias, float* __restrict__ out){
  __shared__ int   sbuf[4][64];
  __shared__ float wbuf[4][64][4];
  const int lane = threadIdx.x & 63;
  const int wid  = threadIdx.x >> 6;
  const int n = blockIdx.x*4 + wid;
  if (n >= N_NODES) return;
  const int rs = row_start[n], re = row_start[n+1];
  const float4 edn = *(const float4*)(ed + n*4);
  const int half = lane >> 5;        // 0: even edge slot, 1: odd
  const int l5   = lane & 31;        // feature block: feats l5*8..l5*8+7
  const int hh   = l5 >> 3;          // head of my feature block
  const unsigned voff_lane = (unsigned)(l5 << 3);  // element offset within row

  float4 sum4 = make_float4(0.f,0.f,0.f,0.f);
  float a0=0.f,a1=0.f,a2=0.f,a3=0.f,a4=0.f,a5=0.f,a6=0.f,a7=0.f;

  for (int base = rs; base < re; base += 64){
    const int cl = min(64, re - base);
    // stage: one edge per lane
    int e = base + lane;
    int s = (e < re) ? csr_src[e] : 0;
    float4 e4 = *(const float4*)(es + (s<<2));
    float w0 = __expf(lrelu(e4.x + edn.x));
    float w1 = __expf(lrelu(e4.y + edn.y));
    float w2 = __expf(lrelu(e4.z + edn.z));
    float w3 = __expf(lrelu(e4.w + edn.w));
    if (e >= re){ w0=0.f; w1=0.f; w2=0.f; w3=0.f; }
    sum4.x += w0; sum4.y += w1; sum4.z += w2; sum4.w += w3;
    sbuf[wid][lane] = s;
    float4 wv4; wv4.x=w0; wv4.y=w1; wv4.z=w2; wv4.w=w3;
    *(float4*)wbuf[wid][lane] = wv4;
    // consume: 2 edges per iteration (lanes 0-31 edge j, lanes 32-63 edge j+1)
    for (int j = 0; j < cl; j += 2){
      int jj = j + half;            // jj==cl (odd cl, half=1) is safe: w=0 there
      float a  = wbuf[wid][jj][hh];
      int   s2 = sbuf[wid][jj];
      uint4 hv = *(const uint4*)(h + ((unsigned)(s2<<8) + voff_lane));
      a0 = fmaf(a, bflo(hv.x), a0);
      a1 = fmaf(a, bfhi(hv.x), a1);
      a2 = fmaf(a, bflo(hv.y), a2);
      a3 = fmaf(a, bfhi(hv.y), a3);
      a4 = fmaf(a, bflo(hv.z), a4);
      a5 = fmaf(a, bfhi(hv.z), a5);
      a6 = fmaf(a, bflo(hv.w), a6);
      a7 = fmaf(a, bfhi(hv.w), a7);
    }
  }
  // total weight per head across all lanes
  #pragma unroll
  for (int off = 32; off >= 1; off >>= 1){
    sum4.x += __shfl_xor(sum4.x, off);
    sum4.y += __shfl_xor(sum4.y, off);
    sum4.z += __shfl_xor(sum4.z, off);
    sum4.w += __shfl_xor(sum4.w, off);
  }
  const float inv = 1.f / (sel4(sum4, hh) + 1e-16f);
  // combine even/odd edge halves (features duplicated across half)
  a0 += __shfl_xor(a0, 32); a1 += __shfl_xor(a1, 32);
  a2 += __shfl_xor(a2, 32); a3 += __shfl_xor(a3, 32);
  a4 += __shfl_xor(a4, 32); a5 += __shfl_xor(a5, 32);
  a6 += __shfl_xor(a6, 32); a7 += __shfl_xor(a7, 32);
  // lane<32 stores feats l5*8..+3 ; lane>=32 stores l5*8+4..+7
  float4 o;
  o.x = (half ? a4 : a0) * inv;
  o.y = (half ? a5 : a1) * inv;
  o.z = (half ? a6 : a2) * inv;
  o.w = (half ? a7 : a3) * inv;
  const int fbase = l5*8 + half*4;
  if (ACT){
    float4 b4 = *(const float4*)(bias + fbase);
    o.x += b4.x; o.y += b4.y; o.z += b4.z; o.w += b4.w;
    o.x = o.x > 0.f ? o.x : expm1f(o.x);
    o.y = o.y > 0.f ? o.y : expm1f(o.y);
    o.z = o.z > 0.f ? o.z : expm1f(o.z);
    o.w = o.w > 0.f ? o.w : expm1f(o.w);
  }
  *(float4*)(out + (size_t)n*HC + fbase) = o;
}

// ---------------- head-mean + global mean pool (sorted-batch register accumulate) ----------------
#define PB_NODES 128
__global__ __launch_bounds__(256) void pool_k(const float* __restrict__ xagg,
                                              const int* __restrict__ batch, float* __restrict__ pooled,
                                              float* __restrict__ cnt){
  int c = threadIdx.x & 63;
  int sub = threadIdx.x >> 6;           // 0..3
  int n0 = blockIdx.x * PB_NODES;
  int nend = n0 + PB_NODES; if (nend > N_NODES) nend = N_NODES;
  float acc = 0.f; int curg = -1; int cl = 0;
  for (int n = n0 + sub; n < nend; n += 4){
    int g = batch[n];
    if (g != curg){
      if (curg >= 0){
        unsafeAtomicAdd(pooled + curg*HID + c, acc);
        if (c == 0) unsafeAtomicAdd(cnt + curg, (float)cl);
      }
      curg = g; acc = 0.f; cl = 0;
    }
    const float* r = xagg + (size_t)n*HC;
    acc += 0.25f*(r[c] + r[64+c] + r[128+c] + r[192+c]);
    cl++;
  }
  if (curg >= 0){
    unsafeAtomicAdd(pooled + curg*HID + c, acc);
    if (c == 0) unsafeAtomicAdd(cnt + curg, (float)cl);
  }
}

// ---------------- MLP head (b2 folded in: mean(x+b2) = mean(x)+b2) ----------------
__global__ __launch_bounds__(64) void mlp_k(const float* __restrict__ pooled, const float* __restrict__ cnt,
                                            const float* __restrict__ b2,
                                            const float* __restrict__ mW1, const float* __restrict__ mb1,
                                            const float* __restrict__ mW2, const float* __restrict__ mb2,
                                            float* __restrict__ out){
  __shared__ float p[HID], h1[HID];
  int g = blockIdx.x, j = threadIdx.x;
  float c = fmaxf(cnt[g], 1.f);
  p[j] = pooled[g*HID + j] / c + b2[j];
  __syncthreads();
  float acc = mb1[j];
  #pragma unroll 8
  for (int k = 0; k < HID; k++) acc = fmaf(p[k], mW1[k*HID + j], acc);
  h1[j] = fmaxf(acc, 0.f);
  __syncthreads();
  if (j < OUT_DIM){
    float a2 = mb2[j];
    #pragma unroll 8
    for (int k = 0; k < HID; k++) a2 = fmaf(h1[k], mW2[k*OUT_DIM + j], a2);
    out[g*OUT_DIM + j] = a2;
  }
}

extern "C" void kernel_launch(void* const* d_in, const int* in_sizes, int n_in,
                              void* d_out, int out_size, void* d_ws, size_t ws_size,
                              hipStream_t stream){
  const float* imgs  = (const float*)d_in[0];
  const int*   ei    = (const int*)d_in[1];
  const int*   batch = (const int*)d_in[2];
  const float* W_agg = (const float*)d_in[3];
  const float* b_agg = (const float*)d_in[4];
  const float* W0 = (const float*)d_in[5];
  const float* as0 = (const float*)d_in[6];
  const float* ad0 = (const float*)d_in[7];
  const float* b0 = (const float*)d_in[8];
  const float* W1 = (const float*)d_in[9];
  const float* as1 = (const float*)d_in[10];
  const float* ad1 = (const float*)d_in[11];
  const float* b1 = (const float*)d_in[12];
  const float* W2 = (const float*)d_in[13];
  const float* as2 = (const float*)d_in[14];
  const float* ad2 = (const float*)d_in[15];
  const float* b2 = (const float*)d_in[16];
  const float* mW1 = (const float*)d_in[17];
  const float* mb1 = (const float*)d_in[18];
  const float* mW2 = (const float*)d_in[19];
  const float* mb2 = (const float*)d_in[20];
  float* out = (float*)d_out;

  // workspace layout
  float* bufA = (float*)d_ws;                                 // N*256 f32
  float* bufBf = bufA + (size_t)N_NODES*HC;                   // region reused as bf16 h
  unsigned short* hb = (unsigned short*)bufBf;                // N*256 bf16
  float* es   = bufBf + (size_t)N_NODES*HC;                   // N*4
  float* ed   = es + (size_t)N_NODES*HEADS;                   // N*4
  float* pooled = ed + (size_t)N_NODES*HEADS;                 // 64*64
  float* cnt  = pooled + N_GRAPHS*HID;                        // 64
  int* row_start = (int*)(cnt + N_GRAPHS);                    // N+1
  int* cursor    = row_start + (N_NODES+1);                   // N
  int* csr_src   = cursor + N_NODES;                          // E_TOT
  int* excl      = csr_src + E_TOT;                           // N
  int* partials  = excl + N_NODES;                            // 256

  const int EB = (E_TOT + 255)/256;
  const int NB = (N_NODES + 255)/256;   // 196

  // CSR build (by dst)
  hipMemsetAsync(cursor, 0, N_NODES*sizeof(int), stream);
  hist_k<<<EB, 256, 0, stream>>>(ei, cursor);
  scan1_k<<<NB, 256, 0, stream>>>(cursor, excl, partials);
  scan2_k<<<1, 256, 0, stream>>>(partials, NB);
  scan3_k<<<NB, 256, 0, stream>>>(excl, partials, row_start, cursor);
  scatter_k<<<EB, 256, 0, stream>>>(ei, cursor, csr_src);

  // aggregator linear
  agg_lin<<<(N_NODES+3)/4, 256, 0, stream>>>(imgs, W_agg, b_agg, bufA);

  const int LB = (N_NODES + 31)/32;
  const int GB = (N_NODES + 3)/4;

  // layer 0 (K=64)
  lin_k<64><<<LB, 256, 0, stream>>>(bufA, W0, as0, ad0, hb, es, ed);
  gat_agg<1><<<GB, 256, 0, stream>>>(hb, es, ed, row_start, csr_src, b0, bufA);

  // layer 1 (K=256)
  lin_k<256><<<LB, 256, 0, stream>>>(bufA, W1, as1, ad1, hb, es, ed);
  gat_agg<1><<<GB, 256, 0, stream>>>(hb, es, ed, row_start, csr_src, b1, bufA);

  // layer 2 (K=256)
  lin_k<256><<<LB, 256, 0, stream>>>(bufA, W2, as2, ad2, hb, es, ed);
  gat_agg<0><<<GB, 256, 0, stream>>>(hb, es, ed, row_start, csr_src, nullptr, bufA);

  // pool + MLP
  hipMemsetAsync(pooled, 0, (N_GRAPHS*HID + N_GRAPHS)*sizeof(float), stream);
  pool_k<<<(N_NODES + PB_NODES - 1)/PB_NODES, 256, 0, stream>>>(bufA, batch, pooled, cnt);
  mlp_k<<<N_GRAPHS, 64, 0, stream>>>(pooled, cnt, b2, mW1, mb1, mW2, mb2, out);
}

// Round 5
// 726.081 us; speedup vs baseline: 2.5162x; 1.2180x over previous
//
#include <hip/hip_runtime.h>
#include <hip/hip_bf16.h>

#define N_NODES 50000
#define N_EDGESX 1600000
#define E_TOT   (N_EDGESX + N_NODES)
#define IN_DIM 128
#define HID 64
#define HEADS 4
#define HC 256
#define N_GRAPHS 64
#define OUT_DIM 10
#define NEG_SLOPE 0.2f

#define NBUK 196          // ceil(N_NODES/256)
#define CAP 12288         // per-bucket capacity (mean ~8673, sigma ~93 -> 38 sigma headroom)
#define BT 4096           // edges staged per bin_k block

__device__ __forceinline__ float lrelu(float x){ return fmaxf(x, NEG_SLOPE*x); }
__device__ __forceinline__ float sel4(float4 v, int i){
  float r = v.x;
  r = (i==1) ? v.y : r;
  r = (i==2) ? v.z : r;
  r = (i==3) ? v.w : r;
  return r;
}
__device__ __forceinline__ unsigned short f2bf(float f){
  union { __hip_bfloat16 b; unsigned short u; } cv;
  cv.b = __float2bfloat16(f);
  return cv.u;
}
__device__ __forceinline__ float bflo(unsigned int u){ return __uint_as_float(u << 16); }
__device__ __forceinline__ float bfhi(unsigned int u){ return __uint_as_float(u & 0xffff0000u); }

// ---------------- CSR build v2: LDS-binned counting sort ----------------
// phase 1: bin edges into 196 buckets of 256 dst nodes, packed (src<<16)|dst
__global__ __launch_bounds__(256) void bin_k(const int* __restrict__ ei,
                                             int* __restrict__ bucket_cursor,
                                             unsigned int* __restrict__ bucket_buf){
  __shared__ unsigned int pk[BT];
  __shared__ unsigned int binned[BT];
  __shared__ int hist[256], excl[256], gbase[256], lcur[256], tmp[256];
  const int tid = threadIdx.x;
  const int e0 = blockIdx.x * BT;
  const int nv = min(BT, E_TOT - e0);
  hist[tid] = 0;
  __syncthreads();
  for (int i = tid; i < nv; i += 256){
    int e = e0 + i;
    int src, dst;
    if (e < N_EDGESX){ src = ei[e]; dst = ei[N_EDGESX + e]; }
    else { src = e - N_EDGESX; dst = src; }
    pk[i] = ((unsigned)src << 16) | (unsigned)dst;
    atomicAdd(&hist[dst >> 8], 1);
  }
  __syncthreads();
  int v = hist[tid];
  tmp[tid] = v;
  __syncthreads();
  for (int off = 1; off < 256; off <<= 1){
    int t = (tid >= off) ? tmp[tid-off] : 0;
    __syncthreads();
    tmp[tid] += t;
    __syncthreads();
  }
  excl[tid] = tmp[tid] - v;
  lcur[tid] = tmp[tid] - v;
  if (tid < NBUK && v > 0) gbase[tid] = atomicAdd(&bucket_cursor[tid], v);
  __syncthreads();
  // scatter into bucket order in LDS
  for (int i = tid; i < nv; i += 256){
    unsigned u = pk[i];
    int b = (int)((u & 0xFFFFu) >> 8);
    int p = atomicAdd(&lcur[b], 1);
    binned[p] = u;
  }
  __syncthreads();
  // flush coalesced runs to per-bucket global regions
  for (int j = tid; j < nv; j += 256){
    unsigned u = binned[j];
    int b = (int)((u & 0xFFFFu) >> 8);
    bucket_buf[(size_t)b*CAP + gbase[b] + (j - excl[b])] = u;
  }
}

// phase 1b: exclusive scan of bucket counts -> global CSR base per bucket
__global__ __launch_bounds__(256) void bucket_scan_k(const int* __restrict__ bucket_cursor,
                                                     int* __restrict__ bucket_base,
                                                     int* __restrict__ row_start){
  __shared__ int tmp[256];
  int t = threadIdx.x;
  int v = (t < NBUK) ? bucket_cursor[t] : 0;
  tmp[t] = v;
  __syncthreads();
  for (int off = 1; off < 256; off <<= 1){
    int x = (t >= off) ? tmp[t-off] : 0;
    __syncthreads();
    tmp[t] += x;
    __syncthreads();
  }
  if (t < NBUK) bucket_base[t] = tmp[t] - v;
  if (t == 0) row_start[N_NODES] = E_TOT;
}

// phase 2: per-bucket local counting sort -> row_start + csr_src
__global__ __launch_bounds__(256) void build_k(const unsigned int* __restrict__ bucket_buf,
                                               const int* __restrict__ bucket_cursor,
                                               const int* __restrict__ bucket_base,
                                               int* __restrict__ row_start,
                                               int* __restrict__ csr_src){
  __shared__ int hist[256], excl[256], lcur[256], tmp[256];
  const int b = blockIdx.x;
  const int t = threadIdx.x;
  const int cntb = bucket_cursor[b];
  const int base = bucket_base[b];
  const unsigned int* buf = bucket_buf + (size_t)b*CAP;
  hist[t] = 0;
  __syncthreads();
  for (int i = t; i < cntb; i += 256) atomicAdd(&hist[buf[i] & 255], 1);
  __syncthreads();
  int v = hist[t];
  tmp[t] = v;
  __syncthreads();
  for (int off = 1; off < 256; off <<= 1){
    int x = (t >= off) ? tmp[t-off] : 0;
    __syncthreads();
    tmp[t] += x;
    __syncthreads();
  }
  excl[t] = tmp[t] - v;
  lcur[t] = tmp[t] - v;
  int g = b*256 + t;
  if (g < N_NODES) row_start[g] = base + excl[t];
  __syncthreads();
  for (int i = t; i < cntb; i += 256){
    unsigned u = buf[i];
    int p = atomicAdd(&lcur[u & 255], 1);
    csr_src[base + p] = (int)(u >> 16);
  }
}

// ---------------- aggregator linear: x0 = imgs @ W_agg + b_agg  [N,64] f32 ----------------
__global__ __launch_bounds__(256) void agg_lin(const float* __restrict__ imgs, const float* __restrict__ W,
                                               const float* __restrict__ b, float* __restrict__ x0){
  __shared__ __align__(16) float xr[4][IN_DIM];
  int w = threadIdx.x >> 6, lane = threadIdx.x & 63;
  int n = blockIdx.x*4 + w;
  if (n >= N_NODES) return;
  ((float2*)xr[w])[lane] = ((const float2*)(imgs + (size_t)n*IN_DIM))[lane];
  float acc = b[lane];
  #pragma unroll 8
  for (int k = 0; k < IN_DIM; k++)
    acc = fmaf(xr[w][k], W[k*HID + lane], acc);
  x0[(size_t)n*HID + lane] = acc;
}

// ---------------- GAT linear + fused attention scores ----------------
template<int K>
__global__ __launch_bounds__(256) void lin_k(const float* __restrict__ x, const float* __restrict__ W,
                                             const float* __restrict__ as_, const float* __restrict__ ad_,
                                             unsigned short* __restrict__ h,
                                             float* __restrict__ es, float* __restrict__ ed){
  __shared__ __align__(16) float xs[K][36];
  const int tid = threadIdx.x;
  const int cg = tid & 63;   // column group: cols cg*4..cg*4+3 (head = cg>>4)
  const int ng = tid >> 6;   // wave id: nodes ng*8..ng*8+7
  const int n0 = blockIdx.x * 32;
  for (int idx = tid; idx < 32*K; idx += 256){
    int r = idx / K, c = idx % K;
    int n = n0 + r;
    xs[c][r] = (n < N_NODES) ? x[(size_t)n*K + c] : 0.f;
  }
  __syncthreads();
  float acc[8][4];
  #pragma unroll
  for (int i = 0; i < 8; i++){
    acc[i][0]=0.f; acc[i][1]=0.f; acc[i][2]=0.f; acc[i][3]=0.f;
  }
  #pragma unroll 4
  for (int k = 0; k < K; k++){
    float4 wv = *(const float4*)(W + k*HC + cg*4);
    float4 a0 = *(const float4*)(&xs[k][ng*8]);
    float4 a1 = *(const float4*)(&xs[k][ng*8+4]);
    float xr[8] = {a0.x,a0.y,a0.z,a0.w,a1.x,a1.y,a1.z,a1.w};
    #pragma unroll
    for (int i = 0; i < 8; i++){
      acc[i][0] = fmaf(xr[i], wv.x, acc[i][0]);
      acc[i][1] = fmaf(xr[i], wv.y, acc[i][1]);
      acc[i][2] = fmaf(xr[i], wv.z, acc[i][2]);
      acc[i][3] = fmaf(xr[i], wv.w, acc[i][3]);
    }
  }
  // fused scores: per node i, per head (16-lane group)
  float4 asv = *(const float4*)(as_ + cg*4);
  float4 adv = *(const float4*)(ad_ + cg*4);
  #pragma unroll
  for (int i = 0; i < 8; i++){
    float ps = acc[i][0]*asv.x + acc[i][1]*asv.y + acc[i][2]*asv.z + acc[i][3]*asv.w;
    float pd = acc[i][0]*adv.x + acc[i][1]*adv.y + acc[i][2]*adv.z + acc[i][3]*adv.w;
    #pragma unroll
    for (int off = 8; off >= 1; off >>= 1){
      ps += __shfl_xor(ps, off);
      pd += __shfl_xor(pd, off);
    }
    int n = n0 + ng*8 + i;
    if ((cg & 15) == 0 && n < N_NODES){
      es[n*4 + (cg>>4)] = ps;
      ed[n*4 + (cg>>4)] = pd;
    }
  }
  #pragma unroll
  for (int i = 0; i < 8; i++){
    int n = n0 + ng*8 + i;
    if (n < N_NODES){
      ushort4 o;
      o.x = f2bf(acc[i][0]); o.y = f2bf(acc[i][1]);
      o.z = f2bf(acc[i][2]); o.w = f2bf(acc[i][3]);
      *(ushort4*)(h + (size_t)n*HC + cg*4) = o;
    }
  }
}

// ---------------- GAT aggregation: single pass, no segment-max, chunked LDS staging ----------------
template<int ACT>
__global__ __launch_bounds__(256) void gat_agg(const unsigned short* __restrict__ h,
    const float* __restrict__ es, const float* __restrict__ ed,
    const int* __restrict__ row_start, const int* __restrict__ csr_src,
    const float* __restrict__ bias, float* __restrict__ out){
  __shared__ int   sbuf[4][64];
  __shared__ float wbuf[4][64][4];
  const int lane = threadIdx.x & 63;
  const int wid  = threadIdx.x >> 6;
  const int n = blockIdx.x*4 + wid;
  if (n >= N_NODES) return;
  const int rs = row_start[n], re = row_start[n+1];
  const float4 edn = *(const float4*)(ed + n*4);
  const int half = lane >> 5;
  const int l5   = lane & 31;
  const int hh   = l5 >> 3;
  const unsigned voff_lane = (unsigned)(l5 << 3);

  float4 sum4 = make_float4(0.f,0.f,0.f,0.f);
  float a0=0.f,a1=0.f,a2=0.f,a3=0.f,a4=0.f,a5=0.f,a6=0.f,a7=0.f;

  for (int base = rs; base < re; base += 64){
    const int cl = min(64, re - base);
    int e = base + lane;
    int s = (e < re) ? csr_src[e] : 0;
    float4 e4 = *(const float4*)(es + (s<<2));
    float w0 = __expf(lrelu(e4.x + edn.x));
    float w1 = __expf(lrelu(e4.y + edn.y));
    float w2 = __expf(lrelu(e4.z + edn.z));
    float w3 = __expf(lrelu(e4.w + edn.w));
    if (e >= re){ w0=0.f; w1=0.f; w2=0.f; w3=0.f; }
    sum4.x += w0; sum4.y += w1; sum4.z += w2; sum4.w += w3;
    sbuf[wid][lane] = s;
    float4 wv4; wv4.x=w0; wv4.y=w1; wv4.z=w2; wv4.w=w3;
    *(float4*)wbuf[wid][lane] = wv4;
    for (int j = 0; j < cl; j += 2){
      int jj = j + half;
      float a  = wbuf[wid][jj][hh];
      int   s2 = sbuf[wid][jj];
      uint4 hv = *(const uint4*)(h + ((unsigned)(s2<<8) + voff_lane));
      a0 = fmaf(a, bflo(hv.x), a0);
      a1 = fmaf(a, bfhi(hv.x), a1);
      a2 = fmaf(a, bflo(hv.y), a2);
      a3 = fmaf(a, bfhi(hv.y), a3);
      a4 = fmaf(a, bflo(hv.z), a4);
      a5 = fmaf(a, bfhi(hv.z), a5);
      a6 = fmaf(a, bflo(hv.w), a6);
      a7 = fmaf(a, bfhi(hv.w), a7);
    }
  }
  #pragma unroll
  for (int off = 32; off >= 1; off >>= 1){
    sum4.x += __shfl_xor(sum4.x, off);
    sum4.y += __shfl_xor(sum4.y, off);
    sum4.z += __shfl_xor(sum4.z, off);
    sum4.w += __shfl_xor(sum4.w, off);
  }
  const float inv = 1.f / (sel4(sum4, hh) + 1e-16f);
  a0 += __shfl_xor(a0, 32); a1 += __shfl_xor(a1, 32);
  a2 += __shfl_xor(a2, 32); a3 += __shfl_xor(a3, 32);
  a4 += __shfl_xor(a4, 32); a5 += __shfl_xor(a5, 32);
  a6 += __shfl_xor(a6, 32); a7 += __shfl_xor(a7, 32);
  float4 o;
  o.x = (half ? a4 : a0) * inv;
  o.y = (half ? a5 : a1) * inv;
  o.z = (half ? a6 : a2) * inv;
  o.w = (half ? a7 : a3) * inv;
  const int fbase = l5*8 + half*4;
  if (ACT){
    float4 b4 = *(const float4*)(bias + fbase);
    o.x += b4.x; o.y += b4.y; o.z += b4.z; o.w += b4.w;
    o.x = o.x > 0.f ? o.x : expm1f(o.x);
    o.y = o.y > 0.f ? o.y : expm1f(o.y);
    o.z = o.z > 0.f ? o.z : expm1f(o.z);
    o.w = o.w > 0.f ? o.w : expm1f(o.w);
  }
  *(float4*)(out + (size_t)n*HC + fbase) = o;
}

// ---------------- head-mean + global mean pool ----------------
#define PB_NODES 128
__global__ __launch_bounds__(256) void pool_k(const float* __restrict__ xagg,
                                              const int* __restrict__ batch, float* __restrict__ pooled,
                                              float* __restrict__ cnt){
  int c = threadIdx.x & 63;
  int sub = threadIdx.x >> 6;
  int n0 = blockIdx.x * PB_NODES;
  int nend = n0 + PB_NODES; if (nend > N_NODES) nend = N_NODES;
  float acc = 0.f; int curg = -1; int cl = 0;
  for (int n = n0 + sub; n < nend; n += 4){
    int g = batch[n];
    if (g != curg){
      if (curg >= 0){
        unsafeAtomicAdd(pooled + curg*HID + c, acc);
        if (c == 0) unsafeAtomicAdd(cnt + curg, (float)cl);
      }
      curg = g; acc = 0.f; cl = 0;
    }
    const float* r = xagg + (size_t)n*HC;
    acc += 0.25f*(r[c] + r[64+c] + r[128+c] + r[192+c]);
    cl++;
  }
  if (curg >= 0){
    unsafeAtomicAdd(pooled + curg*HID + c, acc);
    if (c == 0) unsafeAtomicAdd(cnt + curg, (float)cl);
  }
}

// ---------------- MLP head ----------------
__global__ __launch_bounds__(64) void mlp_k(const float* __restrict__ pooled, const float* __restrict__ cnt,
                                            const float* __restrict__ b2,
                                            const float* __restrict__ mW1, const float* __restrict__ mb1,
                                            const float* __restrict__ mW2, const float* __restrict__ mb2,
                                            float* __restrict__ out){
  __shared__ float p[HID], h1[HID];
  int g = blockIdx.x, j = threadIdx.x;
  float c = fmaxf(cnt[g], 1.f);
  p[j] = pooled[g*HID + j] / c + b2[j];
  __syncthreads();
  float acc = mb1[j];
  #pragma unroll 8
  for (int k = 0; k < HID; k++) acc = fmaf(p[k], mW1[k*HID + j], acc);
  h1[j] = fmaxf(acc, 0.f);
  __syncthreads();
  if (j < OUT_DIM){
    float a2 = mb2[j];
    #pragma unroll 8
    for (int k = 0; k < HID; k++) a2 = fmaf(h1[k], mW2[k*OUT_DIM + j], a2);
    out[g*OUT_DIM + j] = a2;
  }
}

extern "C" void kernel_launch(void* const* d_in, const int* in_sizes, int n_in,
                              void* d_out, int out_size, void* d_ws, size_t ws_size,
                              hipStream_t stream){
  const float* imgs  = (const float*)d_in[0];
  const int*   ei    = (const int*)d_in[1];
  const int*   batch = (const int*)d_in[2];
  const float* W_agg = (const float*)d_in[3];
  const float* b_agg = (const float*)d_in[4];
  const float* W0 = (const float*)d_in[5];
  const float* as0 = (const float*)d_in[6];
  const float* ad0 = (const float*)d_in[7];
  const float* b0 = (const float*)d_in[8];
  const float* W1 = (const float*)d_in[9];
  const float* as1 = (const float*)d_in[10];
  const float* ad1 = (const float*)d_in[11];
  const float* b1 = (const float*)d_in[12];
  const float* W2 = (const float*)d_in[13];
  const float* as2 = (const float*)d_in[14];
  const float* ad2 = (const float*)d_in[15];
  const float* b2 = (const float*)d_in[16];
  const float* mW1 = (const float*)d_in[17];
  const float* mb1 = (const float*)d_in[18];
  const float* mW2 = (const float*)d_in[19];
  const float* mb2 = (const float*)d_in[20];
  float* out = (float*)d_out;

  // workspace layout
  float* bufA = (float*)d_ws;                                 // N*256 f32
  float* bufBf = bufA + (size_t)N_NODES*HC;                   // reused as bf16 h (N*256 bf16)
  unsigned short* hb = (unsigned short*)bufBf;
  float* es   = bufBf + (size_t)N_NODES*HC;                   // N*4
  float* ed   = es + (size_t)N_NODES*HEADS;                   // N*4
  float* pooled = ed + (size_t)N_NODES*HEADS;                 // 64*64
  float* cnt  = pooled + N_GRAPHS*HID;                        // 64
  int* row_start = (int*)(cnt + N_GRAPHS);                    // N+1
  int* csr_src   = row_start + (N_NODES+1);                   // E_TOT
  int* bucket_cursor = csr_src + E_TOT;                       // NBUK
  int* bucket_base   = bucket_cursor + NBUK;                  // NBUK
  unsigned int* bucket_buf = (unsigned int*)(bucket_base + NBUK); // NBUK*CAP (~9.6MB)

  // CSR build v2
  hipMemsetAsync(bucket_cursor, 0, NBUK*sizeof(int), stream);
  bin_k<<<(E_TOT + BT - 1)/BT, 256, 0, stream>>>(ei, bucket_cursor, bucket_buf);
  bucket_scan_k<<<1, 256, 0, stream>>>(bucket_cursor, bucket_base, row_start);
  build_k<<<NBUK, 256, 0, stream>>>(bucket_buf, bucket_cursor, bucket_base, row_start, csr_src);

  // aggregator linear
  agg_lin<<<(N_NODES+3)/4, 256, 0, stream>>>(imgs, W_agg, b_agg, bufA);

  const int LB = (N_NODES + 31)/32;
  const int GB = (N_NODES + 3)/4;

  // layer 0 (K=64)
  lin_k<64><<<LB, 256, 0, stream>>>(bufA, W0, as0, ad0, hb, es, ed);
  gat_agg<1><<<GB, 256, 0, stream>>>(hb, es, ed, row_start, csr_src, b0, bufA);

  // layer 1 (K=256)
  lin_k<256><<<LB, 256, 0, stream>>>(bufA, W1, as1, ad1, hb, es, ed);
  gat_agg<1><<<GB, 256, 0, stream>>>(hb, es, ed, row_start, csr_src, b1, bufA);

  // layer 2 (K=256)
  lin_k<256><<<LB, 256, 0, stream>>>(bufA, W2, as2, ad2, hb, es, ed);
  gat_agg<0><<<GB, 256, 0, stream>>>(hb, es, ed, row_start, csr_src, nullptr, bufA);

  // pool + MLP
  hipMemsetAsync(pooled, 0, (N_GRAPHS*HID + N_GRAPHS)*sizeof(float), stream);
  pool_k<<<(N_NODES + PB_NODES - 1)/PB_NODES, 256, 0, stream>>>(bufA, batch, pooled, cnt);
  mlp_k<<<N_GRAPHS, 64, 0, stream>>>(pooled, cnt, b2, mW1, mb1, mW2, mb2, out);
}

// Round 6
// 620.113 us; speedup vs baseline: 2.9462x; 1.1709x over previous
//
#include <hip/hip_runtime.h>
#include <hip/hip_bf16.h>

#define N_NODES 50000
#define N_EDGESX 1600000
#define E_TOT   (N_EDGESX + N_NODES)
#define IN_DIM 128
#define HID 64
#define HEADS 4
#define HC 256
#define N_GRAPHS 64
#define OUT_DIM 10
#define NEG_SLOPE 0.2f

#define NBUK 196
#define CAP 12288
#define BT 4096

typedef __attribute__((ext_vector_type(8))) short bf16x8;
typedef __attribute__((ext_vector_type(4))) float f32x4;

__device__ __forceinline__ float lrelu(float x){ return fmaxf(x, NEG_SLOPE*x); }
__device__ __forceinline__ float sel4(float4 v, int i){
  float r = v.x;
  r = (i==1) ? v.y : r;
  r = (i==2) ? v.z : r;
  r = (i==3) ? v.w : r;
  return r;
}
__device__ __forceinline__ unsigned short f2bf(float f){
  union { __hip_bfloat16 b; unsigned short u; } cv;
  cv.b = __float2bfloat16(f);
  return cv.u;
}
__device__ __forceinline__ float bflo(unsigned int u){ return __uint_as_float(u << 16); }
__device__ __forceinline__ float bfhi(unsigned int u){ return __uint_as_float(u & 0xffff0000u); }

// ---------------- CSR build: LDS-binned counting sort ----------------
__global__ __launch_bounds__(256) void bin_k(const int* __restrict__ ei,
                                             int* __restrict__ bucket_cursor,
                                             unsigned int* __restrict__ bucket_buf){
  __shared__ unsigned int pk[BT];
  __shared__ unsigned int binned[BT];
  __shared__ int hist[256], excl[256], gbase[256], lcur[256], tmp[256];
  const int tid = threadIdx.x;
  const int e0 = blockIdx.x * BT;
  const int nv = min(BT, E_TOT - e0);
  hist[tid] = 0;
  __syncthreads();
  for (int i = tid; i < nv; i += 256){
    int e = e0 + i;
    int src, dst;
    if (e < N_EDGESX){ src = ei[e]; dst = ei[N_EDGESX + e]; }
    else { src = e - N_EDGESX; dst = src; }
    pk[i] = ((unsigned)src << 16) | (unsigned)dst;
    atomicAdd(&hist[dst >> 8], 1);
  }
  __syncthreads();
  int v = hist[tid];
  tmp[tid] = v;
  __syncthreads();
  for (int off = 1; off < 256; off <<= 1){
    int t = (tid >= off) ? tmp[tid-off] : 0;
    __syncthreads();
    tmp[tid] += t;
    __syncthreads();
  }
  excl[tid] = tmp[tid] - v;
  lcur[tid] = tmp[tid] - v;
  if (tid < NBUK && v > 0) gbase[tid] = atomicAdd(&bucket_cursor[tid], v);
  __syncthreads();
  for (int i = tid; i < nv; i += 256){
    unsigned u = pk[i];
    int b = (int)((u & 0xFFFFu) >> 8);
    int p = atomicAdd(&lcur[b], 1);
    binned[p] = u;
  }
  __syncthreads();
  for (int j = tid; j < nv; j += 256){
    unsigned u = binned[j];
    int b = (int)((u & 0xFFFFu) >> 8);
    bucket_buf[(size_t)b*CAP + gbase[b] + (j - excl[b])] = u;
  }
}

__global__ __launch_bounds__(256) void bucket_scan_k(const int* __restrict__ bucket_cursor,
                                                     int* __restrict__ bucket_base,
                                                     int* __restrict__ row_start){
  __shared__ int tmp[256];
  int t = threadIdx.x;
  int v = (t < NBUK) ? bucket_cursor[t] : 0;
  tmp[t] = v;
  __syncthreads();
  for (int off = 1; off < 256; off <<= 1){
    int x = (t >= off) ? tmp[t-off] : 0;
    __syncthreads();
    tmp[t] += x;
    __syncthreads();
  }
  if (t < NBUK) bucket_base[t] = tmp[t] - v;
  if (t == 0) row_start[N_NODES] = E_TOT;
}

__global__ __launch_bounds__(256) void build_k(const unsigned int* __restrict__ bucket_buf,
                                               const int* __restrict__ bucket_cursor,
                                               const int* __restrict__ bucket_base,
                                               int* __restrict__ row_start,
                                               int* __restrict__ csr_src){
  __shared__ int hist[256], excl[256], lcur[256], tmp[256];
  const int b = blockIdx.x;
  const int t = threadIdx.x;
  const int cntb = bucket_cursor[b];
  const int base = bucket_base[b];
  const unsigned int* buf = bucket_buf + (size_t)b*CAP;
  hist[t] = 0;
  __syncthreads();
  for (int i = t; i < cntb; i += 256) atomicAdd(&hist[buf[i] & 255], 1);
  __syncthreads();
  int v = hist[t];
  tmp[t] = v;
  __syncthreads();
  for (int off = 1; off < 256; off <<= 1){
    int x = (t >= off) ? tmp[t-off] : 0;
    __syncthreads();
    tmp[t] += x;
    __syncthreads();
  }
  excl[t] = tmp[t] - v;
  lcur[t] = tmp[t] - v;
  int g = b*256 + t;
  if (g < N_NODES) row_start[g] = base + excl[t];
  __syncthreads();
  for (int i = t; i < cntb; i += 256){
    unsigned u = buf[i];
    int p = atomicAdd(&lcur[u & 255], 1);
    csr_src[base + p] = (int)(u >> 16);
  }
}

// ---------------- weight transpose+bf16 convert: WT[c][k] = bf16(W[k][c]) ----------------
__global__ __launch_bounds__(256) void wcvt_k(const float* __restrict__ W, unsigned short* __restrict__ WT, int K){
  int idx = blockIdx.x*256 + threadIdx.x;
  if (idx >= K*256) return;
  int k = idx >> 8, c = idx & 255;
  WT[c*K + k] = f2bf(W[k*256 + c]);
}

// ---------------- aggregator linear: x0 = bf16(imgs @ W_agg + b_agg)  [N,64] ----------------
__global__ __launch_bounds__(256) void agg_lin(const float* __restrict__ imgs, const float* __restrict__ W,
                                               const float* __restrict__ b, unsigned short* __restrict__ x0){
  __shared__ __align__(16) float xr[4][IN_DIM];
  int w = threadIdx.x >> 6, lane = threadIdx.x & 63;
  int n = blockIdx.x*4 + w;
  if (n >= N_NODES) return;
  ((float2*)xr[w])[lane] = ((const float2*)(imgs + (size_t)n*IN_DIM))[lane];
  float acc = b[lane];
  #pragma unroll 8
  for (int k = 0; k < IN_DIM; k++)
    acc = fmaf(xr[w][k], W[k*HID + lane], acc);
  x0[(size_t)n*HID + lane] = f2bf(acc);
}

// ---------------- MFMA GAT linear + fused attention scores ----------------
// x: [N,K] bf16. WT: [256][K] bf16 (W transposed). h: [N,256] bf16. es/ed: [N,4] f32.
// Block: 256 thr = 4 waves; 16 nodes/block; wave w owns cols w*64..w*64+63 (== head w).
template<int K>
__global__ __launch_bounds__(256) void lin_mfma(const unsigned short* __restrict__ x,
                                                const unsigned short* __restrict__ WT,
                                                const float* __restrict__ as_, const float* __restrict__ ad_,
                                                unsigned short* __restrict__ h,
                                                float* __restrict__ es, float* __restrict__ ed){
  constexpr int KP = K + 8;          // +16B pad -> 2-way LDS conflicts only
  __shared__ __align__(16) unsigned short xs[16][KP];
  const int tid = threadIdx.x;
  const int lane = tid & 63;
  const int w = tid >> 6;            // wave = head = col block
  const int n0 = blockIdx.x * 16;
  // stage A tile (16 x K bf16), 8-ushort chunks
  constexpr int CH = K/8;
  for (int i = tid; i < 16*CH; i += 256){
    int r = i / CH, cc = (i % CH)*8;
    *(uint4*)(&xs[r][cc]) = *(const uint4*)(x + (size_t)(n0+r)*K + cc);
  }
  __syncthreads();
  const int g  = lane >> 4;          // k sub-group / row group
  const int cl = lane & 15;          // A row / B col-in-tile
  f32x4 acc[4];
  #pragma unroll
  for (int c = 0; c < 4; c++) acc[c] = (f32x4){0.f,0.f,0.f,0.f};
  #pragma unroll
  for (int t = 0; t < K/32; t++){
    bf16x8 a = *(const bf16x8*)(&xs[cl][t*32 + g*8]);
    #pragma unroll
    for (int c = 0; c < 4; c++){
      bf16x8 bv = *(const bf16x8*)(WT + (size_t)(w*64 + c*16 + cl)*K + t*32 + g*8);
      acc[c] = __builtin_amdgcn_mfma_f32_16x16x32_bf16(a, bv, acc[c], 0, 0, 0);
    }
  }
  // scores: es[n,w] = sum_c h[n, w*64+c] * as[w*64+c]  (acc: col=cl+16c, row=g*4+j)
  float pes[4] = {0.f,0.f,0.f,0.f}, ped[4] = {0.f,0.f,0.f,0.f};
  #pragma unroll
  for (int c = 0; c < 4; c++){
    float av = as_[w*64 + c*16 + cl];
    float dv = ad_[w*64 + c*16 + cl];
    #pragma unroll
    for (int j = 0; j < 4; j++){
      pes[j] = fmaf(acc[c][j], av, pes[j]);
      ped[j] = fmaf(acc[c][j], dv, ped[j]);
    }
  }
  #pragma unroll
  for (int off = 8; off >= 1; off >>= 1){
    #pragma unroll
    for (int j = 0; j < 4; j++){
      pes[j] += __shfl_xor(pes[j], off);
      ped[j] += __shfl_xor(ped[j], off);
    }
  }
  if (cl == 0){
    #pragma unroll
    for (int j = 0; j < 4; j++){
      int n = n0 + g*4 + j;
      es[n*4 + w] = pes[j];
      ed[n*4 + w] = ped[j];
    }
  }
  // store h bf16: row = g*4+j, col = w*64 + c*16 + cl
  #pragma unroll
  for (int c = 0; c < 4; c++){
    #pragma unroll
    for (int j = 0; j < 4; j++){
      h[(size_t)(n0 + g*4 + j)*HC + w*64 + c*16 + cl] = f2bf(acc[c][j]);
    }
  }
}

// ---------------- GAT aggregation: single pass, chunked LDS staging ----------------
// OBF: 1 -> write bf16 (next layer input), 0 -> write f32 (pool input)
template<int ACT, int OBF>
__global__ __launch_bounds__(256) void gat_agg(const unsigned short* __restrict__ h,
    const float* __restrict__ es, const float* __restrict__ ed,
    const int* __restrict__ row_start, const int* __restrict__ csr_src,
    const float* __restrict__ bias, void* __restrict__ outp){
  __shared__ int   sbuf[4][64];
  __shared__ float wbuf[4][64][4];
  const int lane = threadIdx.x & 63;
  const int wid  = threadIdx.x >> 6;
  const int n = blockIdx.x*4 + wid;
  if (n >= N_NODES) return;
  const int rs = row_start[n], re = row_start[n+1];
  const float4 edn = *(const float4*)(ed + n*4);
  const int half = lane >> 5;
  const int l5   = lane & 31;
  const int hh   = l5 >> 3;
  const unsigned voff_lane = (unsigned)(l5 << 3);

  float4 sum4 = make_float4(0.f,0.f,0.f,0.f);
  float a0=0.f,a1=0.f,a2=0.f,a3=0.f,a4=0.f,a5=0.f,a6=0.f,a7=0.f;

  for (int base = rs; base < re; base += 64){
    const int cl = min(64, re - base);
    int e = base + lane;
    int s = (e < re) ? csr_src[e] : 0;
    float4 e4 = *(const float4*)(es + (s<<2));
    float w0 = __expf(lrelu(e4.x + edn.x));
    float w1 = __expf(lrelu(e4.y + edn.y));
    float w2 = __expf(lrelu(e4.z + edn.z));
    float w3 = __expf(lrelu(e4.w + edn.w));
    if (e >= re){ w0=0.f; w1=0.f; w2=0.f; w3=0.f; }
    sum4.x += w0; sum4.y += w1; sum4.z += w2; sum4.w += w3;
    sbuf[wid][lane] = s;
    float4 wv4; wv4.x=w0; wv4.y=w1; wv4.z=w2; wv4.w=w3;
    *(float4*)wbuf[wid][lane] = wv4;
    for (int j = 0; j < cl; j += 2){
      int jj = j + half;
      float a  = wbuf[wid][jj][hh];
      int   s2 = sbuf[wid][jj];
      uint4 hv = *(const uint4*)(h + ((unsigned)(s2<<8) + voff_lane));
      a0 = fmaf(a, bflo(hv.x), a0);
      a1 = fmaf(a, bfhi(hv.x), a1);
      a2 = fmaf(a, bflo(hv.y), a2);
      a3 = fmaf(a, bfhi(hv.y), a3);
      a4 = fmaf(a, bflo(hv.z), a4);
      a5 = fmaf(a, bfhi(hv.z), a5);
      a6 = fmaf(a, bflo(hv.w), a6);
      a7 = fmaf(a, bfhi(hv.w), a7);
    }
  }
  #pragma unroll
  for (int off = 32; off >= 1; off >>= 1){
    sum4.x += __shfl_xor(sum4.x, off);
    sum4.y += __shfl_xor(sum4.y, off);
    sum4.z += __shfl_xor(sum4.z, off);
    sum4.w += __shfl_xor(sum4.w, off);
  }
  const float inv = 1.f / (sel4(sum4, hh) + 1e-16f);
  a0 += __shfl_xor(a0, 32); a1 += __shfl_xor(a1, 32);
  a2 += __shfl_xor(a2, 32); a3 += __shfl_xor(a3, 32);
  a4 += __shfl_xor(a4, 32); a5 += __shfl_xor(a5, 32);
  a6 += __shfl_xor(a6, 32); a7 += __shfl_xor(a7, 32);
  float4 o;
  o.x = (half ? a4 : a0) * inv;
  o.y = (half ? a5 : a1) * inv;
  o.z = (half ? a6 : a2) * inv;
  o.w = (half ? a7 : a3) * inv;
  const int fbase = l5*8 + half*4;
  if (ACT){
    float4 b4 = *(const float4*)(bias + fbase);
    o.x += b4.x; o.y += b4.y; o.z += b4.z; o.w += b4.w;
    o.x = o.x > 0.f ? o.x : expm1f(o.x);
    o.y = o.y > 0.f ? o.y : expm1f(o.y);
    o.z = o.z > 0.f ? o.z : expm1f(o.z);
    o.w = o.w > 0.f ? o.w : expm1f(o.w);
  }
  if (OBF){
    ushort4 ob;
    ob.x = f2bf(o.x); ob.y = f2bf(o.y); ob.z = f2bf(o.z); ob.w = f2bf(o.w);
    *(ushort4*)((unsigned short*)outp + (size_t)n*HC + fbase) = ob;
  } else {
    *(float4*)((float*)outp + (size_t)n*HC + fbase) = o;
  }
}

// ---------------- head-mean + global mean pool ----------------
#define PB_NODES 128
__global__ __launch_bounds__(256) void pool_k(const float* __restrict__ xagg,
                                              const int* __restrict__ batch, float* __restrict__ pooled,
                                              float* __restrict__ cnt){
  int c = threadIdx.x & 63;
  int sub = threadIdx.x >> 6;
  int n0 = blockIdx.x * PB_NODES;
  int nend = n0 + PB_NODES; if (nend > N_NODES) nend = N_NODES;
  float acc = 0.f; int curg = -1; int cl = 0;
  for (int n = n0 + sub; n < nend; n += 4){
    int g = batch[n];
    if (g != curg){
      if (curg >= 0){
        unsafeAtomicAdd(pooled + curg*HID + c, acc);
        if (c == 0) unsafeAtomicAdd(cnt + curg, (float)cl);
      }
      curg = g; acc = 0.f; cl = 0;
    }
    const float* r = xagg + (size_t)n*HC;
    acc += 0.25f*(r[c] + r[64+c] + r[128+c] + r[192+c]);
    cl++;
  }
  if (curg >= 0){
    unsafeAtomicAdd(pooled + curg*HID + c, acc);
    if (c == 0) unsafeAtomicAdd(cnt + curg, (float)cl);
  }
}

// ---------------- MLP head ----------------
__global__ __launch_bounds__(64) void mlp_k(const float* __restrict__ pooled, const float* __restrict__ cnt,
                                            const float* __restrict__ b2,
                                            const float* __restrict__ mW1, const float* __restrict__ mb1,
                                            const float* __restrict__ mW2, const float* __restrict__ mb2,
                                            float* __restrict__ out){
  __shared__ float p[HID], h1[HID];
  int g = blockIdx.x, j = threadIdx.x;
  float c = fmaxf(cnt[g], 1.f);
  p[j] = pooled[g*HID + j] / c + b2[j];
  __syncthreads();
  float acc = mb1[j];
  #pragma unroll 8
  for (int k = 0; k < HID; k++) acc = fmaf(p[k], mW1[k*HID + j], acc);
  h1[j] = fmaxf(acc, 0.f);
  __syncthreads();
  if (j < OUT_DIM){
    float a2 = mb2[j];
    #pragma unroll 8
    for (int k = 0; k < HID; k++) a2 = fmaf(h1[k], mW2[k*OUT_DIM + j], a2);
    out[g*OUT_DIM + j] = a2;
  }
}

extern "C" void kernel_launch(void* const* d_in, const int* in_sizes, int n_in,
                              void* d_out, int out_size, void* d_ws, size_t ws_size,
                              hipStream_t stream){
  const float* imgs  = (const float*)d_in[0];
  const int*   ei    = (const int*)d_in[1];
  const int*   batch = (const int*)d_in[2];
  const float* W_agg = (const float*)d_in[3];
  const float* b_agg = (const float*)d_in[4];
  const float* W0 = (const float*)d_in[5];
  const float* as0 = (const float*)d_in[6];
  const float* ad0 = (const float*)d_in[7];
  const float* b0 = (const float*)d_in[8];
  const float* W1 = (const float*)d_in[9];
  const float* as1 = (const float*)d_in[10];
  const float* ad1 = (const float*)d_in[11];
  const float* b1 = (const float*)d_in[12];
  const float* W2 = (const float*)d_in[13];
  const float* as2 = (const float*)d_in[14];
  const float* ad2 = (const float*)d_in[15];
  const float* b2 = (const float*)d_in[16];
  const float* mW1 = (const float*)d_in[17];
  const float* mb1 = (const float*)d_in[18];
  const float* mW2 = (const float*)d_in[19];
  const float* mb2 = (const float*)d_in[20];
  float* out = (float*)d_out;

  // workspace layout
  float* xf32 = (float*)d_ws;                                  // N*256 f32 (layer2 out -> pool)
  unsigned short* hb  = (unsigned short*)(xf32 + (size_t)N_NODES*HC);  // N*256 bf16
  unsigned short* xbf = hb + (size_t)N_NODES*HC;               // N*256 bf16 (x0 uses first N*64)
  float* es   = (float*)(xbf + (size_t)N_NODES*HC);            // N*4
  float* ed   = es + (size_t)N_NODES*HEADS;                    // N*4
  float* pooled = ed + (size_t)N_NODES*HEADS;                  // 64*64
  float* cnt  = pooled + N_GRAPHS*HID;                         // 64
  int* row_start = (int*)(cnt + N_GRAPHS);                     // N+1
  int* csr_src   = row_start + (N_NODES+1);                    // E_TOT
  int* bucket_cursor = csr_src + E_TOT;                        // NBUK
  int* bucket_base   = bucket_cursor + NBUK;                   // NBUK
  unsigned short* WT0 = (unsigned short*)(bucket_base + NBUK); // 256*64
  unsigned short* WT1 = WT0 + 256*64;                          // 256*256
  unsigned short* WT2 = WT1 + 256*256;                         // 256*256
  unsigned int* bucket_buf = (unsigned int*)(WT2 + 256*256);   // NBUK*CAP

  // CSR build
  hipMemsetAsync(bucket_cursor, 0, NBUK*sizeof(int), stream);
  bin_k<<<(E_TOT + BT - 1)/BT, 256, 0, stream>>>(ei, bucket_cursor, bucket_buf);
  bucket_scan_k<<<1, 256, 0, stream>>>(bucket_cursor, bucket_base, row_start);
  build_k<<<NBUK, 256, 0, stream>>>(bucket_buf, bucket_cursor, bucket_base, row_start, csr_src);

  // weight conversions (bf16, transposed)
  wcvt_k<<<(64*256+255)/256, 256, 0, stream>>>(W0, WT0, 64);
  wcvt_k<<<(256*256+255)/256, 256, 0, stream>>>(W1, WT1, 256);
  wcvt_k<<<(256*256+255)/256, 256, 0, stream>>>(W2, WT2, 256);

  // aggregator linear -> bf16 x0
  agg_lin<<<(N_NODES+3)/4, 256, 0, stream>>>(imgs, W_agg, b_agg, xbf);

  const int MB = N_NODES/16;            // 3125
  const int GB = (N_NODES + 3)/4;

  // layer 0 (K=64)
  lin_mfma<64><<<MB, 256, 0, stream>>>(xbf, WT0, as0, ad0, hb, es, ed);
  gat_agg<1,1><<<GB, 256, 0, stream>>>(hb, es, ed, row_start, csr_src, b0, xbf);

  // layer 1 (K=256)
  lin_mfma<256><<<MB, 256, 0, stream>>>(xbf, WT1, as1, ad1, hb, es, ed);
  gat_agg<1,1><<<GB, 256, 0, stream>>>(hb, es, ed, row_start, csr_src, b1, xbf);

  // layer 2 (K=256) -> f32 out for pool
  lin_mfma<256><<<MB, 256, 0, stream>>>(xbf, WT2, as2, ad2, hb, es, ed);
  gat_agg<0,0><<<GB, 256, 0, stream>>>(hb, es, ed, row_start, csr_src, nullptr, xf32);

  // pool + MLP
  hipMemsetAsync(pooled, 0, (N_GRAPHS*HID + N_GRAPHS)*sizeof(float), stream);
  pool_k<<<(N_NODES + PB_NODES - 1)/PB_NODES, 256, 0, stream>>>(xf32, batch, pooled, cnt);
  mlp_k<<<N_GRAPHS, 64, 0, stream>>>(pooled, cnt, b2, mW1, mb1, mW2, mb2, out);
}